// Round 17
// baseline (237.562 us; speedup 1.0000x reference)
//
#include <hip/hip_runtime.h>

// Problem constants (B,S,H,NH,P) = (2,2048,1024,16,64)
#define B_ 2
#define S_ 2048
#define H_ 1024
#define NH_ 16
#define P_ 64

using f32x4 = __attribute__((ext_vector_type(4))) float;
using i32x4 = __attribute__((ext_vector_type(4))) int;
using f16   = _Float16;
using f16x8 = __attribute__((ext_vector_type(8))) f16;
using f16x4 = __attribute__((ext_vector_type(4))) f16;
using h16x2 = __attribute__((ext_vector_type(2))) __fp16;   // cvt_pkrtz return type

#define QSCALE 0.18033688f   // 0.125 * log2(e): exp(s/8) = exp2(s*QSCALE)

static __device__ __forceinline__ f16x8 ldh8(const f16* p) { return *(const f16x8*)p; }
static __device__ __forceinline__ f32x4 ld4f(const float* p) { return *(const f32x4*)p; }

static __device__ __forceinline__ f32x4 mm16(f16x8 a, f16x8 b, f32x4 c) {
  return __builtin_amdgcn_mfma_f32_16x16x32_f16(a, b, c, 0, 0, 0);
}

// ---------------------------------------------------------------------------
// Prep A: transpose W [NH][3][H][P] fp32 -> Wt fp16 [NH][3][P][H]
// ---------------------------------------------------------------------------
__global__ __launch_bounds__(256) void tw_kernel(
    const float* __restrict__ W, f16* __restrict__ WtH)
{
  __shared__ float T[64 * 65];
  const int tid = threadIdx.x;
  const int nt = blockIdx.x >> 4;
  const int h0 = (blockIdx.x & 15) * 64;
  const float* src = W + (size_t)nt * H_ * P_ + (size_t)h0 * P_;
  #pragma unroll
  for (int r = 0; r < 4; ++r) {
    int idx = tid + r * 256;
    int h = idx >> 4, p4 = (idx & 15) << 2;
    f32x4 v = ld4f(src + (size_t)h * P_ + p4);
    #pragma unroll
    for (int i = 0; i < 4; ++i) T[(p4 + i) * 65 + h] = v[i];
  }
  __syncthreads();
  f16* dh = WtH + (size_t)nt * P_ * H_;
  #pragma unroll
  for (int r = 0; r < 4; ++r) {
    int idx = tid + r * 256;
    int p = idx >> 4, h4 = (idx & 15) << 2;
    f16x4 hv;
    #pragma unroll
    for (int i = 0; i < 4; ++i) hv[i] = (f16)T[p * 65 + h4 + i];
    *(f16x4*)(dh + (size_t)p * H_ + h0 + h4) = hv;
  }
}

// ---------------------------------------------------------------------------
// Prep B: convert Wl [H][H] fp32 -> fp16
// ---------------------------------------------------------------------------
__global__ __launch_bounds__(256) void swl_kernel(
    const float* __restrict__ Wl, f16* __restrict__ WlH)
{
  int idx = blockIdx.x * 256 + threadIdx.x;
  f32x4 v = ((const f32x4*)Wl)[idx];
  f16x4 h;
  #pragma unroll
  for (int i = 0; i < 4; ++i) h[i] = (f16)v[i];
  ((f16x4*)WlH)[idx] = h;
}

// ---------------------------------------------------------------------------
// Kernel 1: QKV via single fp16 MFMA. x tile (64s x 64k) staged fp16 in LDS,
// double-buffered, chunk-XOR swizzled. Q pre-scaled by 0.125*log2e.
// ---------------------------------------------------------------------------
__global__ __launch_bounds__(256) void qkv_kernel(
    const float* __restrict__ x, const f16* __restrict__ WtH,
    f16* __restrict__ Kh, f16* __restrict__ Qh, f16* __restrict__ VTh)
{
  __shared__ f16 xls[2][64 * 64];

  int blk = blockIdx.x;
  const int st = blk & 31; blk >>= 5;
  const int n = blk & 15;
  const int b = blk >> 4;
  const int s0 = st * 64;
  const int tid = threadIdx.x;
  const int w = tid >> 6, lane = tid & 63, q = lane >> 4, fr = lane & 15;
  const int bn = b * NH_ + n;

  const int srow = tid >> 2, scc = tid & 3;
  const float* xsrc = x + ((size_t)b * S_ + s0 + srow) * H_ + 16 * scc;
  const int c0 = ((2 * scc) ^ (srow & 7)) * 8;
  const int c1 = ((2 * scc + 1) ^ (srow & 7)) * 8;

  auto stage = [&](int k0, int bs) {
    f32x4 v0 = ld4f(xsrc + k0),     v1 = ld4f(xsrc + k0 + 4);
    f32x4 v2 = ld4f(xsrc + k0 + 8), v3 = ld4f(xsrc + k0 + 12);
    f16x8 a, b2;
    #pragma unroll
    for (int e = 0; e < 4; ++e) {
      a[e] = (f16)v0[e];  a[e + 4] = (f16)v1[e];
      b2[e] = (f16)v2[e]; b2[e + 4] = (f16)v3[e];
    }
    *(f16x8*)&xls[bs][srow * 64 + c0] = a;
    *(f16x8*)&xls[bs][srow * 64 + c1] = b2;
  };

  const f16* WtK = WtH + ((size_t)(n * 3 + 0) * P_ + 16 * w + fr) * H_ + 8 * q;
  const f16* WtV = WtH + ((size_t)(n * 3 + 1) * P_ + 16 * w + fr) * H_ + 8 * q;
  const f16* WtQ = WtH + ((size_t)(n * 3 + 2) * P_ + 16 * w + fr) * H_ + 8 * q;

  f32x4 accK[4] = {}, accQ[4] = {}, accV[4] = {};

  stage(0, 0);
  for (int step = 0; step < 16; ++step) {
    __syncthreads();
    if (step < 15) stage((step + 1) * 64, (step + 1) & 1);
    const int bs = step & 1;
    const int k0 = step * 64;

    f16x8 xf[4][2];
    #pragma unroll
    for (int ss = 0; ss < 4; ++ss) {
      int row = 16 * ss + fr;
      #pragma unroll
      for (int ks = 0; ks < 2; ++ks) {
        int ch = ((q + 4 * ks) ^ (row & 7)) * 8;
        xf[ss][ks] = *(const f16x8*)&xls[bs][row * 64 + ch];
      }
    }
    f16x8 wk0 = ldh8(WtK + k0), wk1 = ldh8(WtK + k0 + 32);
    f16x8 wq0 = ldh8(WtQ + k0), wq1 = ldh8(WtQ + k0 + 32);
    f16x8 wv0 = ldh8(WtV + k0), wv1 = ldh8(WtV + k0 + 32);
    #pragma unroll
    for (int ss = 0; ss < 4; ++ss) {
      accK[ss] = mm16(wk0, xf[ss][0], accK[ss]);
      accK[ss] = mm16(wk1, xf[ss][1], accK[ss]);
      accQ[ss] = mm16(wq0, xf[ss][0], accQ[ss]);
      accQ[ss] = mm16(wq1, xf[ss][1], accQ[ss]);
      accV[ss] = mm16(xf[ss][0], wv0, accV[ss]);
      accV[ss] = mm16(xf[ss][1], wv1, accV[ss]);
    }
  }

  #pragma unroll
  for (int ss = 0; ss < 4; ++ss) {
    f16x4 hK, hQ;
    #pragma unroll
    for (int c = 0; c < 4; ++c) {
      hK[c] = (f16)accK[ss][c];
      hQ[c] = (f16)(accQ[ss][c] * QSCALE);
    }
    size_t off = ((size_t)bn * S_ + (s0 + 16 * ss + fr)) * P_ + 16 * w + 4 * q;
    *(f16x4*)(Kh + off) = hK;
    *(f16x4*)(Qh + off) = hQ;
  }
  #pragma unroll
  for (int ss = 0; ss < 4; ++ss) {
    f16x4 hV;
    #pragma unroll
    for (int c = 0; c < 4; ++c) hV[c] = (f16)accV[ss][c];
    size_t off = ((size_t)bn * P_ + (16 * w + fr)) * S_ + s0 + 16 * ss + 4 * q;
    *(f16x4*)(VTh + off) = hV;
  }
}

// ---------------------------------------------------------------------------
// Kernel 2: column sum-exp2, j-tile 128 (grid 512). Per-lane accumulation,
// double-buffered K prefetch, no loop barriers.
// ---------------------------------------------------------------------------
__global__ __launch_bounds__(256) void stats_kernel(
    const f16* __restrict__ Kh, const f16* __restrict__ Qh,
    float* __restrict__ csuminv)
{
  __shared__ float zbuf[2 * 128];
  const int tid = threadIdx.x;
  const int bid = blockIdx.x;
  const int j0 = (bid & 15) * 128;
  const int bn = bid >> 4;
  const int w = tid >> 6, lane = tid & 63, q = lane >> 4, fr = lane & 15;
  const int jb = 64 * (w & 1), ih = w >> 1, ib0 = 32 * ih;

  f16x8 qf[4][2];
  #pragma unroll
  for (int jt = 0; jt < 4; ++jt)
    #pragma unroll
    for (int ks = 0; ks < 2; ++ks)
      qf[jt][ks] = ldh8(Qh + ((size_t)bn * S_ + (j0 + jb + 16 * jt + fr)) * P_ + 8 * q + 32 * ks);

  f32x4 z[4] = {};
  f16x8 kA[2][2], kB[2][2];

  auto loadK = [&](f16x8 (&kf)[2][2], int i0) {
    #pragma unroll
    for (int it = 0; it < 2; ++it)
      #pragma unroll
      for (int ks = 0; ks < 2; ++ks)
        kf[it][ks] = ldh8(Kh + ((size_t)bn * S_ + (i0 + ib0 + 16 * it + fr)) * P_ + 8 * q + 32 * ks);
  };
  auto step = [&](f16x8 (&kf)[2][2]) {
    f32x4 sc[4][2] = {};
    __builtin_amdgcn_s_setprio(1);
    #pragma unroll
    for (int ks = 0; ks < 2; ++ks)
      #pragma unroll
      for (int jt = 0; jt < 4; ++jt)
        #pragma unroll
        for (int it = 0; it < 2; ++it)
          sc[jt][it] = mm16(qf[jt][ks], kf[it][ks], sc[jt][it]);
    __builtin_amdgcn_s_setprio(0);
    #pragma unroll
    for (int jt = 0; jt < 4; ++jt)
      #pragma unroll
      for (int c = 0; c < 4; ++c)
        z[jt][c] += exp2f(sc[jt][0][c]) + exp2f(sc[jt][1][c]);
  };

  loadK(kA, 0);
  for (int i0 = 0; i0 < S_; i0 += 128) {
    loadK(kB, i0 + 64);
    step(kA);
    loadK(kA, (i0 + 128) & (S_ - 1));
    step(kB);
  }

  #pragma unroll
  for (int msk = 1; msk <= 8; msk <<= 1)
    #pragma unroll
    for (int jt = 0; jt < 4; ++jt)
      #pragma unroll
      for (int c = 0; c < 4; ++c)
        z[jt][c] += __shfl_xor(z[jt][c], msk, 64);

  if (fr == 0) {
    #pragma unroll
    for (int jt = 0; jt < 4; ++jt)
      *(f32x4*)&zbuf[ih * 128 + jb + 16 * jt + 4 * q] = z[jt];
  }
  __syncthreads();
  if (tid < 128)
    csuminv[(size_t)bn * S_ + j0 + tid] = 1.0f / (zbuf[tid] + zbuf[128 + tid]);
}

// ---------------------------------------------------------------------------
// Kernel 2.5: V' = mask ? zinv*V : 0 (in-place on VT); C[bn][p] = (1/S)*sum
// of masked-out V. grid = B*NH*16 blocks; wave per p-row.
// ---------------------------------------------------------------------------
__global__ __launch_bounds__(256) void scale_kernel(
    f16* __restrict__ VT, const float* __restrict__ csuminv,
    const int* __restrict__ mask, float* __restrict__ Cbuf)
{
  const int bid = blockIdx.x;
  const int bn = bid >> 4;
  const int b = bn >> 4;
  const int p = (bid & 15) * 4 + (threadIdx.x >> 6);
  const int lane = threadIdx.x & 63;
  f16* row = VT + ((size_t)bn * P_ + p) * S_;
  const float* zr = csuminv + (size_t)bn * S_;
  const int* mr = mask + (size_t)b * S_;
  float acc = 0.0f;
  #pragma unroll
  for (int k = 0; k < 4; ++k) {
    int s = (lane + 64 * k) * 8;
    f16x8 v = *(const f16x8*)(row + s);
    f32x4 z0 = ld4f(zr + s), z1 = ld4f(zr + s + 4);
    i32x4 m0 = *(const i32x4*)(mr + s), m1 = *(const i32x4*)(mr + s + 4);
    f16x8 o;
    #pragma unroll
    for (int e = 0; e < 4; ++e) {
      float fv = (float)v[e];
      if (m0[e] != 0) o[e] = (f16)(fv * z0[e]);
      else { o[e] = (f16)0.0f; acc += fv; }
      float fv2 = (float)v[e + 4];
      if (m1[e] != 0) o[e + 4] = (f16)(fv2 * z1[e]);
      else { o[e + 4] = (f16)0.0f; acc += fv2; }
    }
    *(f16x8*)(row + s) = o;
  }
  #pragma unroll
  for (int msk = 1; msk <= 32; msk <<= 1) acc += __shfl_xor(acc, msk, 64);
  if (lane == 0) Cbuf[bn * P_ + p] = acc * (1.0f / S_);
}

// ---------------------------------------------------------------------------
// Kernel 3: AV pass, barrier-free hot loop, i-tile 128 (grid 512), 4 waves.
// Wave w owns j-slices {T*128 + w*32}, T=0..15. Per step/wave: 32 QK mfma +
// 64 exp2 (pkrtz) + 32 PV mfma, 8 global ld8 (2x R14 math per load).
// Private-E pitch 36 (128 rows); direct hid write + C.
// ---------------------------------------------------------------------------
__global__ __launch_bounds__(256) void av_kernel(
    const f16* __restrict__ Kh, const f16* __restrict__ Qh,
    const f16* __restrict__ VT, const float* __restrict__ Cbuf,
    f16* __restrict__ hidh)
{
  __shared__ __align__(16) char smem[36864];  // max(4*128*36*2, 128*68*4)
  const int tid = threadIdx.x;
  const int bid = blockIdx.x;
  const int i0 = (bid & 15) * 128;
  const int bn = bid >> 4;
  const int b = bn >> 4, n = bn & 15;
  const int w = tid >> 6, lane = tid & 63, q = lane >> 4, fr = lane & 15;
  f16* ew = (f16*)smem + w * (128 * 36);

  // K b-frags fixed: rows i = i0+16it+fr (full 128-i tile)
  f16x8 kf[8][2];
  #pragma unroll
  for (int it = 0; it < 8; ++it)
    #pragma unroll
    for (int ks = 0; ks < 2; ++ks)
      kf[it][ks] = ldh8(Kh + ((size_t)bn * S_ + (i0 + 16 * it + fr)) * P_ + 8 * q + 32 * ks);

  // streaming pointers (j0 = w*32 at T=0)
  const f16* qp  = Qh + ((size_t)bn * S_ + (w * 32 + fr)) * P_ + 8 * q;
  const f16* vp0 = VT + ((size_t)bn * P_ + fr) * S_ + w * 32 + 8 * q;
  const f16* vp1 = vp0 + (size_t)16 * S_;
  const f16* vp2 = vp0 + (size_t)32 * S_;
  const f16* vp3 = vp0 + (size_t)48 * S_;

  f32x4 opv[4][8] = {};   // [pt][it]: p = 16pt+4q+c, i = 16it+fr

  for (int T = 0; T < 16; ++T) {
    f16x8 aq00 = ldh8(qp);           // jt=0 ks=0
    f16x8 aq01 = ldh8(qp + 32);      // jt=0 ks=1
    f16x8 aq10 = ldh8(qp + 1024);    // jt=1 ks=0  (16 rows * 64)
    f16x8 aq11 = ldh8(qp + 1056);    // jt=1 ks=1
    f16x8 va0 = ldh8(vp0), va1 = ldh8(vp1), va2 = ldh8(vp2), va3 = ldh8(vp3);
    qp += 128 * 64;
    vp0 += 128; vp1 += 128; vp2 += 128; vp3 += 128;

    #pragma unroll
    for (int it = 0; it < 8; ++it) {
      f32x4 s0 = {}, s1 = {};
      s0 = mm16(aq00, kf[it][0], s0);
      s0 = mm16(aq01, kf[it][1], s0);
      s1 = mm16(aq10, kf[it][0], s1);
      s1 = mm16(aq11, kf[it][1], s1);
      union { f16x4 v; h16x2 h[2]; } e0, e1;
      e0.h[0] = __builtin_amdgcn_cvt_pkrtz(exp2f(s0[0]), exp2f(s0[1]));
      e0.h[1] = __builtin_amdgcn_cvt_pkrtz(exp2f(s0[2]), exp2f(s0[3]));
      e1.h[0] = __builtin_amdgcn_cvt_pkrtz(exp2f(s1[0]), exp2f(s1[1]));
      e1.h[1] = __builtin_amdgcn_cvt_pkrtz(exp2f(s1[2]), exp2f(s1[3]));
      *(f16x4*)(ew + (16 * it + fr) * 36 + 4 * q)      = e0.v;
      *(f16x4*)(ew + (16 * it + fr) * 36 + 16 + 4 * q) = e1.v;
    }

    #pragma unroll
    for (int it = 0; it < 8; ++it) {
      f16x8 ef = *(const f16x8*)(ew + (16 * it + fr) * 36 + 8 * q);
      opv[0][it] = mm16(va0, ef, opv[0][it]);
      opv[1][it] = mm16(va1, ef, opv[1][it]);
      opv[2][it] = mm16(va2, ef, opv[2][it]);
      opv[3][it] = mm16(va3, ef, opv[3][it]);
    }
  }

  // ---- epilogue: reduce 4 wave-partials via LDS (reuses smem as f32 acc) ----
  float* accl = (float*)smem;   // [128][68] pitch 68
  #pragma unroll
  for (int r = 0; r < 4; ++r) {
    __syncthreads();
    if (w == r) {
      #pragma unroll
      for (int it = 0; it < 8; ++it)
        #pragma unroll
        for (int pt = 0; pt < 4; ++pt) {
          float* a = &accl[(16 * it + fr) * 68 + 16 * pt + 4 * q];
          if (r == 0) *(f32x4*)a = opv[pt][it];
          else {
            f32x4 old = *(const f32x4*)a;
            #pragma unroll
            for (int c = 0; c < 4; ++c) old[c] += opv[pt][it][c];
            *(f32x4*)a = old;
          }
        }
    }
  }
  __syncthreads();

  // write hid: thread -> (i = tid>>1, p-half tp = (tid&1)*32), 32 f16
  const int ti = tid >> 1;
  const int tp = (tid & 1) << 5;
  const float* cb = Cbuf + bn * P_ + tp;
  f16* dst = hidh + ((size_t)b * S_ + (i0 + ti)) * H_ + n * P_ + tp;
  #pragma unroll
  for (int h = 0; h < 4; ++h) {
    f32x4 a0 = *(const f32x4*)&accl[ti * 68 + tp + 8 * h];
    f32x4 a1 = *(const f32x4*)&accl[ti * 68 + tp + 8 * h + 4];
    f32x4 c0 = ld4f(cb + 8 * h);
    f32x4 c1 = ld4f(cb + 8 * h + 4);
    f16x8 o;
    #pragma unroll
    for (int e = 0; e < 4; ++e) {
      o[e]     = (f16)(a0[e] + c0[e]);
      o[e + 4] = (f16)(a1[e] + c1[e]);
    }
    *(f16x8*)(dst + 8 * h) = o;
  }
}

// ---------------------------------------------------------------------------
// Kernel 4: out = hid @ Wl.T + bl via fp16 MFMA. BK=64, hid tile staged in
// LDS, double-buffered, chunk-XOR swizzled.
// ---------------------------------------------------------------------------
__global__ __launch_bounds__(256) void final_kernel(
    const f16* __restrict__ hidh, const f16* __restrict__ WlH,
    const float* __restrict__ bl, float* __restrict__ out)
{
  __shared__ f16 hl[2][64 * 64];
  const int tid = threadIdx.x;
  const int ot = blockIdx.x & 15;
  const int rt = blockIdx.x >> 4;
  const int r0 = rt * 64, o0 = ot * 64;
  const int w = tid >> 6, lane = tid & 63, q = lane >> 4, fr = lane & 15;

  const int srow = tid >> 2, scc = tid & 3;
  const f16* hsrc = hidh + (size_t)(r0 + srow) * H_ + 16 * scc;
  const int c0 = ((2 * scc) ^ (srow & 7)) * 8;
  const int c1 = ((2 * scc + 1) ^ (srow & 7)) * 8;

  auto stage = [&](int k0, int bs) {
    f16x8 a = ldh8(hsrc + k0);
    f16x8 b2 = ldh8(hsrc + k0 + 8);
    *(f16x8*)&hl[bs][srow * 64 + c0] = a;
    *(f16x8*)&hl[bs][srow * 64 + c1] = b2;
  };

  const f16* WlA = WlH + ((size_t)(o0 + 16 * w + fr)) * H_ + 8 * q;

  f32x4 acc[4] = {};

  stage(0, 0);
  for (int step = 0; step < 16; ++step) {
    __syncthreads();
    if (step < 15) stage((step + 1) * 64, (step + 1) & 1);
    const int bs = step & 1;
    const int k0 = step * 64;

    f16x8 bh[4][2];
    #pragma unroll
    for (int ss = 0; ss < 4; ++ss) {
      int row = 16 * ss + fr;
      #pragma unroll
      for (int ks = 0; ks < 2; ++ks) {
        int ch = ((q + 4 * ks) ^ (row & 7)) * 8;
        bh[ss][ks] = *(const f16x8*)&hl[bs][row * 64 + ch];
      }
    }
    f16x8 ah0 = ldh8(WlA + k0);
    f16x8 ah1 = ldh8(WlA + k0 + 32);
    #pragma unroll
    for (int ss = 0; ss < 4; ++ss) {
      acc[ss] = mm16(ah0, bh[ss][0], acc[ss]);
      acc[ss] = mm16(ah1, bh[ss][1], acc[ss]);
    }
  }

  const int o = o0 + 16 * w + 4 * q;
  f32x4 bv = ld4f(bl + o);
  #pragma unroll
  for (int ss = 0; ss < 4; ++ss) {
    f32x4 v;
    #pragma unroll
    for (int c = 0; c < 4; ++c) v[c] = acc[ss][c] + bv[c];
    *(f32x4*)(out + (size_t)(r0 + 16 * ss + fr) * H_ + o) = v;
  }
}

// ---------------------------------------------------------------------------
extern "C" void kernel_launch(void* const* d_in, const int* in_sizes, int n_in,
                              void* d_out, int out_size, void* d_ws, size_t ws_size,
                              hipStream_t stream) {
  const float* x    = (const float*)d_in[0];
  const int*   mask = (const int*)d_in[1];
  const float* W    = (const float*)d_in[2];
  const float* Wl   = (const float*)d_in[3];
  const float* bl   = (const float*)d_in[4];
  float* out = (float*)d_out;

  const size_t SZ  = (size_t)B_ * NH_ * S_ * P_;      // 4,194,304
  const size_t SZW = (size_t)NH_ * 3 * H_ * P_;       // 3,145,728
  const size_t SZL = (size_t)H_ * H_;                 // 1,048,576
  const size_t SZC = (size_t)B_ * NH_ * S_;           // 65,536
  const size_t SZH = (size_t)B_ * S_ * H_;            // 4,194,304

  char* p = (char*)d_ws;
  f16*   Kh   = (f16*)p;  p += SZ * 2;
  f16*   Qh   = (f16*)p;  p += SZ * 2;
  f16*   VTh  = (f16*)p;  p += SZ * 2;
  f16*   WtH  = (f16*)p;  p += SZW * 2;
  f16*   WlH  = (f16*)p;  p += SZL * 2;
  f16*   hidh = (f16*)p;  p += SZH * 2;
  float* csuminv = (float*)p; p += SZC * 4;
  float* Cbuf    = (float*)p; p += (size_t)B_ * NH_ * P_ * 4;
  // total ~43 MB

  tw_kernel   <<<NH_ * 3 * (H_ / 64), 256, 0, stream>>>(W, WtH);
  swl_kernel  <<<(SZL / 4) / 256, 256, 0, stream>>>(Wl, WlH);
  qkv_kernel  <<<B_ * NH_ * (S_ / 64), 256, 0, stream>>>(x, WtH, Kh, Qh, VTh);
  stats_kernel<<<B_ * NH_ * (S_ / 128), 256, 0, stream>>>(Kh, Qh, csuminv);
  scale_kernel<<<B_ * NH_ * 16, 256, 0, stream>>>(VTh, csuminv, mask, Cbuf);
  av_kernel   <<<B_ * NH_ * (S_ / 128), 256, 0, stream>>>(
      Kh, Qh, VTh, Cbuf, hidh);
  final_kernel<<<(B_ * S_ / 64) * (H_ / 64), 256, 0, stream>>>(
      hidh, WlH, bl, out);
}

// Round 18
// 218.028 us; speedup vs baseline: 1.0896x; 1.0896x over previous
//
#include <hip/hip_runtime.h>

// Problem constants (B,S,H,NH,P) = (2,2048,1024,16,64)
#define B_ 2
#define S_ 2048
#define H_ 1024
#define NH_ 16
#define P_ 64

using f32x4 = __attribute__((ext_vector_type(4))) float;
using i32x4 = __attribute__((ext_vector_type(4))) int;
using f16   = _Float16;
using f16x8 = __attribute__((ext_vector_type(8))) f16;
using f16x4 = __attribute__((ext_vector_type(4))) f16;
using h16x2 = __attribute__((ext_vector_type(2))) __fp16;   // cvt_pkrtz return type

#define QSCALE 0.18033688f   // 0.125 * log2(e): exp(s/8) = exp2(s*QSCALE)

static __device__ __forceinline__ f16x8 ldh8(const f16* p) { return *(const f16x8*)p; }
static __device__ __forceinline__ f32x4 ld4f(const float* p) { return *(const f32x4*)p; }

static __device__ __forceinline__ f32x4 mm16(f16x8 a, f16x8 b, f32x4 c) {
  return __builtin_amdgcn_mfma_f32_16x16x32_f16(a, b, c, 0, 0, 0);
}

// ---------------------------------------------------------------------------
// Prep A: transpose W [NH][3][H][P] fp32 -> Wt fp16 [NH][3][P][H]
// ---------------------------------------------------------------------------
__global__ __launch_bounds__(256) void tw_kernel(
    const float* __restrict__ W, f16* __restrict__ WtH)
{
  __shared__ float T[64 * 65];
  const int tid = threadIdx.x;
  const int nt = blockIdx.x >> 4;
  const int h0 = (blockIdx.x & 15) * 64;
  const float* src = W + (size_t)nt * H_ * P_ + (size_t)h0 * P_;
  #pragma unroll
  for (int r = 0; r < 4; ++r) {
    int idx = tid + r * 256;
    int h = idx >> 4, p4 = (idx & 15) << 2;
    f32x4 v = ld4f(src + (size_t)h * P_ + p4);
    #pragma unroll
    for (int i = 0; i < 4; ++i) T[(p4 + i) * 65 + h] = v[i];
  }
  __syncthreads();
  f16* dh = WtH + (size_t)nt * P_ * H_;
  #pragma unroll
  for (int r = 0; r < 4; ++r) {
    int idx = tid + r * 256;
    int p = idx >> 4, h4 = (idx & 15) << 2;
    f16x4 hv;
    #pragma unroll
    for (int i = 0; i < 4; ++i) hv[i] = (f16)T[p * 65 + h4 + i];
    *(f16x4*)(dh + (size_t)p * H_ + h0 + h4) = hv;
  }
}

// ---------------------------------------------------------------------------
// Prep B: convert Wl [H][H] fp32 -> fp16
// ---------------------------------------------------------------------------
__global__ __launch_bounds__(256) void swl_kernel(
    const float* __restrict__ Wl, f16* __restrict__ WlH)
{
  int idx = blockIdx.x * 256 + threadIdx.x;
  f32x4 v = ((const f32x4*)Wl)[idx];
  f16x4 h;
  #pragma unroll
  for (int i = 0; i < 4; ++i) h[i] = (f16)v[i];
  ((f16x4*)WlH)[idx] = h;
}

// ---------------------------------------------------------------------------
// Kernel 1: QKV via single fp16 MFMA. x tile (64s x 64k) staged fp16 in LDS,
// double-buffered, chunk-XOR swizzled. Q pre-scaled by 0.125*log2e.
// ---------------------------------------------------------------------------
__global__ __launch_bounds__(256) void qkv_kernel(
    const float* __restrict__ x, const f16* __restrict__ WtH,
    f16* __restrict__ Kh, f16* __restrict__ Qh, f16* __restrict__ VTh)
{
  __shared__ f16 xls[2][64 * 64];

  int blk = blockIdx.x;
  const int st = blk & 31; blk >>= 5;
  const int n = blk & 15;
  const int b = blk >> 4;
  const int s0 = st * 64;
  const int tid = threadIdx.x;
  const int w = tid >> 6, lane = tid & 63, q = lane >> 4, fr = lane & 15;
  const int bn = b * NH_ + n;

  const int srow = tid >> 2, scc = tid & 3;
  const float* xsrc = x + ((size_t)b * S_ + s0 + srow) * H_ + 16 * scc;
  const int c0 = ((2 * scc) ^ (srow & 7)) * 8;
  const int c1 = ((2 * scc + 1) ^ (srow & 7)) * 8;

  auto stage = [&](int k0, int bs) {
    f32x4 v0 = ld4f(xsrc + k0),     v1 = ld4f(xsrc + k0 + 4);
    f32x4 v2 = ld4f(xsrc + k0 + 8), v3 = ld4f(xsrc + k0 + 12);
    f16x8 a, b2;
    #pragma unroll
    for (int e = 0; e < 4; ++e) {
      a[e] = (f16)v0[e];  a[e + 4] = (f16)v1[e];
      b2[e] = (f16)v2[e]; b2[e + 4] = (f16)v3[e];
    }
    *(f16x8*)&xls[bs][srow * 64 + c0] = a;
    *(f16x8*)&xls[bs][srow * 64 + c1] = b2;
  };

  const f16* WtK = WtH + ((size_t)(n * 3 + 0) * P_ + 16 * w + fr) * H_ + 8 * q;
  const f16* WtV = WtH + ((size_t)(n * 3 + 1) * P_ + 16 * w + fr) * H_ + 8 * q;
  const f16* WtQ = WtH + ((size_t)(n * 3 + 2) * P_ + 16 * w + fr) * H_ + 8 * q;

  f32x4 accK[4] = {}, accQ[4] = {}, accV[4] = {};

  stage(0, 0);
  for (int step = 0; step < 16; ++step) {
    __syncthreads();
    if (step < 15) stage((step + 1) * 64, (step + 1) & 1);
    const int bs = step & 1;
    const int k0 = step * 64;

    f16x8 xf[4][2];
    #pragma unroll
    for (int ss = 0; ss < 4; ++ss) {
      int row = 16 * ss + fr;
      #pragma unroll
      for (int ks = 0; ks < 2; ++ks) {
        int ch = ((q + 4 * ks) ^ (row & 7)) * 8;
        xf[ss][ks] = *(const f16x8*)&xls[bs][row * 64 + ch];
      }
    }
    f16x8 wk0 = ldh8(WtK + k0), wk1 = ldh8(WtK + k0 + 32);
    f16x8 wq0 = ldh8(WtQ + k0), wq1 = ldh8(WtQ + k0 + 32);
    f16x8 wv0 = ldh8(WtV + k0), wv1 = ldh8(WtV + k0 + 32);
    #pragma unroll
    for (int ss = 0; ss < 4; ++ss) {
      accK[ss] = mm16(wk0, xf[ss][0], accK[ss]);
      accK[ss] = mm16(wk1, xf[ss][1], accK[ss]);
      accQ[ss] = mm16(wq0, xf[ss][0], accQ[ss]);
      accQ[ss] = mm16(wq1, xf[ss][1], accQ[ss]);
      accV[ss] = mm16(xf[ss][0], wv0, accV[ss]);
      accV[ss] = mm16(xf[ss][1], wv1, accV[ss]);
    }
  }

  #pragma unroll
  for (int ss = 0; ss < 4; ++ss) {
    f16x4 hK, hQ;
    #pragma unroll
    for (int c = 0; c < 4; ++c) {
      hK[c] = (f16)accK[ss][c];
      hQ[c] = (f16)(accQ[ss][c] * QSCALE);
    }
    size_t off = ((size_t)bn * S_ + (s0 + 16 * ss + fr)) * P_ + 16 * w + 4 * q;
    *(f16x4*)(Kh + off) = hK;
    *(f16x4*)(Qh + off) = hQ;
  }
  #pragma unroll
  for (int ss = 0; ss < 4; ++ss) {
    f16x4 hV;
    #pragma unroll
    for (int c = 0; c < 4; ++c) hV[c] = (f16)accV[ss][c];
    size_t off = ((size_t)bn * P_ + (16 * w + fr)) * S_ + s0 + 16 * ss + 4 * q;
    *(f16x4*)(VTh + off) = hV;
  }
}

// ---------------------------------------------------------------------------
// Kernel 2: column sum-exp2, j-tile 128 (grid 512). Per-lane accumulation,
// double-buffered K prefetch, no loop barriers.
// ---------------------------------------------------------------------------
__global__ __launch_bounds__(256) void stats_kernel(
    const f16* __restrict__ Kh, const f16* __restrict__ Qh,
    float* __restrict__ csuminv)
{
  __shared__ float zbuf[2 * 128];
  const int tid = threadIdx.x;
  const int bid = blockIdx.x;
  const int j0 = (bid & 15) * 128;
  const int bn = bid >> 4;
  const int w = tid >> 6, lane = tid & 63, q = lane >> 4, fr = lane & 15;
  const int jb = 64 * (w & 1), ih = w >> 1, ib0 = 32 * ih;

  f16x8 qf[4][2];
  #pragma unroll
  for (int jt = 0; jt < 4; ++jt)
    #pragma unroll
    for (int ks = 0; ks < 2; ++ks)
      qf[jt][ks] = ldh8(Qh + ((size_t)bn * S_ + (j0 + jb + 16 * jt + fr)) * P_ + 8 * q + 32 * ks);

  f32x4 z[4] = {};
  f16x8 kA[2][2], kB[2][2];

  auto loadK = [&](f16x8 (&kf)[2][2], int i0) {
    #pragma unroll
    for (int it = 0; it < 2; ++it)
      #pragma unroll
      for (int ks = 0; ks < 2; ++ks)
        kf[it][ks] = ldh8(Kh + ((size_t)bn * S_ + (i0 + ib0 + 16 * it + fr)) * P_ + 8 * q + 32 * ks);
  };
  auto step = [&](f16x8 (&kf)[2][2]) {
    f32x4 sc[4][2] = {};
    __builtin_amdgcn_s_setprio(1);
    #pragma unroll
    for (int ks = 0; ks < 2; ++ks)
      #pragma unroll
      for (int jt = 0; jt < 4; ++jt)
        #pragma unroll
        for (int it = 0; it < 2; ++it)
          sc[jt][it] = mm16(qf[jt][ks], kf[it][ks], sc[jt][it]);
    __builtin_amdgcn_s_setprio(0);
    #pragma unroll
    for (int jt = 0; jt < 4; ++jt)
      #pragma unroll
      for (int c = 0; c < 4; ++c)
        z[jt][c] += exp2f(sc[jt][0][c]) + exp2f(sc[jt][1][c]);
  };

  loadK(kA, 0);
  for (int i0 = 0; i0 < S_; i0 += 128) {
    loadK(kB, i0 + 64);
    step(kA);
    loadK(kA, (i0 + 128) & (S_ - 1));
    step(kB);
  }

  #pragma unroll
  for (int msk = 1; msk <= 8; msk <<= 1)
    #pragma unroll
    for (int jt = 0; jt < 4; ++jt)
      #pragma unroll
      for (int c = 0; c < 4; ++c)
        z[jt][c] += __shfl_xor(z[jt][c], msk, 64);

  if (fr == 0) {
    #pragma unroll
    for (int jt = 0; jt < 4; ++jt)
      *(f32x4*)&zbuf[ih * 128 + jb + 16 * jt + 4 * q] = z[jt];
  }
  __syncthreads();
  if (tid < 128)
    csuminv[(size_t)bn * S_ + j0 + tid] = 1.0f / (zbuf[tid] + zbuf[128 + tid]);
}

// ---------------------------------------------------------------------------
// Kernel 2.5: V' = mask ? zinv*V : 0 (in-place on VT); C[bn][p] = (1/S)*sum
// of masked-out V. grid = B*NH*16 blocks; wave per p-row.
// ---------------------------------------------------------------------------
__global__ __launch_bounds__(256) void scale_kernel(
    f16* __restrict__ VT, const float* __restrict__ csuminv,
    const int* __restrict__ mask, float* __restrict__ Cbuf)
{
  const int bid = blockIdx.x;
  const int bn = bid >> 4;
  const int b = bn >> 4;
  const int p = (bid & 15) * 4 + (threadIdx.x >> 6);
  const int lane = threadIdx.x & 63;
  f16* row = VT + ((size_t)bn * P_ + p) * S_;
  const float* zr = csuminv + (size_t)bn * S_;
  const int* mr = mask + (size_t)b * S_;
  float acc = 0.0f;
  #pragma unroll
  for (int k = 0; k < 4; ++k) {
    int s = (lane + 64 * k) * 8;
    f16x8 v = *(const f16x8*)(row + s);
    f32x4 z0 = ld4f(zr + s), z1 = ld4f(zr + s + 4);
    i32x4 m0 = *(const i32x4*)(mr + s), m1 = *(const i32x4*)(mr + s + 4);
    f16x8 o;
    #pragma unroll
    for (int e = 0; e < 4; ++e) {
      float fv = (float)v[e];
      if (m0[e] != 0) o[e] = (f16)(fv * z0[e]);
      else { o[e] = (f16)0.0f; acc += fv; }
      float fv2 = (float)v[e + 4];
      if (m1[e] != 0) o[e + 4] = (f16)(fv2 * z1[e]);
      else { o[e + 4] = (f16)0.0f; acc += fv2; }
    }
    *(f16x8*)(row + s) = o;
  }
  #pragma unroll
  for (int msk = 1; msk <= 32; msk <<= 1) acc += __shfl_xor(acc, msk, 64);
  if (lane == 0) Cbuf[bn * P_ + p] = acc * (1.0f / S_);
}

// ---------------------------------------------------------------------------
// Kernel 3: AV pass, barrier-free hot loop, i-tile 64, grid 1024, 4 waves.
// Wave w owns j-slices {T*128 + w*32}, T=0..15. Software-pipelined it-chains:
// QKEW(0); {QKEW(it); PV(it-1)}; PV(3) — interleaves PV MFMAs into the
// exp/pkrtz/ds gaps of the next QK chain. Same registers/LDS as R14.
// ---------------------------------------------------------------------------
__global__ __launch_bounds__(256) void av_kernel(
    const f16* __restrict__ Kh, const f16* __restrict__ Qh,
    const f16* __restrict__ VT, const float* __restrict__ Cbuf,
    f16* __restrict__ hidh)
{
  __shared__ __align__(16) char smem[18432];  // max(4*64*36*2, 64*68*4)
  const int tid = threadIdx.x;
  const int bid = blockIdx.x;
  const int i0 = (bid & 31) * 64;
  const int bn = bid >> 5;
  const int b = bn >> 4, n = bn & 15;
  const int w = tid >> 6, lane = tid & 63, q = lane >> 4, fr = lane & 15;
  f16* ew = (f16*)smem + w * (64 * 36);

  // K b-frags fixed: rows i = i0+16it+fr (full 64-i tile)
  f16x8 kf[4][2];
  #pragma unroll
  for (int it = 0; it < 4; ++it)
    #pragma unroll
    for (int ks = 0; ks < 2; ++ks)
      kf[it][ks] = ldh8(Kh + ((size_t)bn * S_ + (i0 + 16 * it + fr)) * P_ + 8 * q + 32 * ks);

  // streaming pointers (j0 = w*32 at T=0)
  const f16* qp  = Qh + ((size_t)bn * S_ + (w * 32 + fr)) * P_ + 8 * q;
  const f16* vp0 = VT + ((size_t)bn * P_ + fr) * S_ + w * 32 + 8 * q;
  const f16* vp1 = vp0 + (size_t)16 * S_;
  const f16* vp2 = vp0 + (size_t)32 * S_;
  const f16* vp3 = vp0 + (size_t)48 * S_;

  f32x4 opv[4][4] = {};   // [pt][it]: p = 16pt+4q+c, i = 16it+fr

  for (int T = 0; T < 16; ++T) {
    f16x8 aq00 = ldh8(qp);           // jt=0 ks=0
    f16x8 aq01 = ldh8(qp + 32);      // jt=0 ks=1
    f16x8 aq10 = ldh8(qp + 1024);    // jt=1 ks=0  (16 rows * 64)
    f16x8 aq11 = ldh8(qp + 1056);    // jt=1 ks=1
    f16x8 va0 = ldh8(vp0), va1 = ldh8(vp1), va2 = ldh8(vp2), va3 = ldh8(vp3);
    qp += 128 * 64;
    vp0 += 128; vp1 += 128; vp2 += 128; vp3 += 128;

    // software-pipelined chains: QKEW(it) interleaved with PV(it-1)
    #pragma unroll
    for (int it = 0; it < 4; ++it) {
      {
        f32x4 s0 = {}, s1 = {};
        s0 = mm16(aq00, kf[it][0], s0);
        s0 = mm16(aq01, kf[it][1], s0);
        s1 = mm16(aq10, kf[it][0], s1);
        s1 = mm16(aq11, kf[it][1], s1);
        union { f16x4 v; h16x2 h[2]; } e0, e1;
        e0.h[0] = __builtin_amdgcn_cvt_pkrtz(exp2f(s0[0]), exp2f(s0[1]));
        e0.h[1] = __builtin_amdgcn_cvt_pkrtz(exp2f(s0[2]), exp2f(s0[3]));
        e1.h[0] = __builtin_amdgcn_cvt_pkrtz(exp2f(s1[0]), exp2f(s1[1]));
        e1.h[1] = __builtin_amdgcn_cvt_pkrtz(exp2f(s1[2]), exp2f(s1[3]));
        *(f16x4*)(ew + (16 * it + fr) * 36 + 4 * q)      = e0.v;
        *(f16x4*)(ew + (16 * it + fr) * 36 + 16 + 4 * q) = e1.v;
      }
      if (it > 0) {
        const int pv = it - 1;
        f16x8 ef = *(const f16x8*)(ew + (16 * pv + fr) * 36 + 8 * q);
        opv[0][pv] = mm16(va0, ef, opv[0][pv]);
        opv[1][pv] = mm16(va1, ef, opv[1][pv]);
        opv[2][pv] = mm16(va2, ef, opv[2][pv]);
        opv[3][pv] = mm16(va3, ef, opv[3][pv]);
      }
    }
    {
      f16x8 ef = *(const f16x8*)(ew + (16 * 3 + fr) * 36 + 8 * q);
      opv[0][3] = mm16(va0, ef, opv[0][3]);
      opv[1][3] = mm16(va1, ef, opv[1][3]);
      opv[2][3] = mm16(va2, ef, opv[2][3]);
      opv[3][3] = mm16(va3, ef, opv[3][3]);
    }
  }

  // ---- epilogue: reduce 4 wave-partials via LDS (reuses smem as f32 acc) ----
  float* accl = (float*)smem;   // [64][68] pitch 68
  #pragma unroll
  for (int r = 0; r < 4; ++r) {
    __syncthreads();
    if (w == r) {
      #pragma unroll
      for (int it = 0; it < 4; ++it)
        #pragma unroll
        for (int pt = 0; pt < 4; ++pt) {
          float* a = &accl[(16 * it + fr) * 68 + 16 * pt + 4 * q];
          if (r == 0) *(f32x4*)a = opv[pt][it];
          else {
            f32x4 old = *(const f32x4*)a;
            #pragma unroll
            for (int c = 0; c < 4; ++c) old[c] += opv[pt][it][c];
            *(f32x4*)a = old;
          }
        }
    }
  }
  __syncthreads();

  const int ti = tid >> 2;
  const int tp = (tid & 3) << 4;
  const float* cb = Cbuf + bn * P_ + tp;
  f16* dst = hidh + ((size_t)b * S_ + (i0 + ti)) * H_ + n * P_ + tp;
  #pragma unroll
  for (int h = 0; h < 2; ++h) {
    f32x4 a0 = *(const f32x4*)&accl[ti * 68 + tp + 8 * h];
    f32x4 a1 = *(const f32x4*)&accl[ti * 68 + tp + 8 * h + 4];
    f32x4 c0 = ld4f(cb + 8 * h);
    f32x4 c1 = ld4f(cb + 8 * h + 4);
    f16x8 o;
    #pragma unroll
    for (int e = 0; e < 4; ++e) {
      o[e]     = (f16)(a0[e] + c0[e]);
      o[e + 4] = (f16)(a1[e] + c1[e]);
    }
    *(f16x8*)(dst + 8 * h) = o;
  }
}

// ---------------------------------------------------------------------------
// Kernel 4: out = hid @ Wl.T + bl via fp16 MFMA. BK=64, hid tile staged in
// LDS, double-buffered, chunk-XOR swizzled.
// ---------------------------------------------------------------------------
__global__ __launch_bounds__(256) void final_kernel(
    const f16* __restrict__ hidh, const f16* __restrict__ WlH,
    const float* __restrict__ bl, float* __restrict__ out)
{
  __shared__ f16 hl[2][64 * 64];
  const int tid = threadIdx.x;
  const int ot = blockIdx.x & 15;
  const int rt = blockIdx.x >> 4;
  const int r0 = rt * 64, o0 = ot * 64;
  const int w = tid >> 6, lane = tid & 63, q = lane >> 4, fr = lane & 15;

  const int srow = tid >> 2, scc = tid & 3;
  const f16* hsrc = hidh + (size_t)(r0 + srow) * H_ + 16 * scc;
  const int c0 = ((2 * scc) ^ (srow & 7)) * 8;
  const int c1 = ((2 * scc + 1) ^ (srow & 7)) * 8;

  auto stage = [&](int k0, int bs) {
    f16x8 a = ldh8(hsrc + k0);
    f16x8 b2 = ldh8(hsrc + k0 + 8);
    *(f16x8*)&hl[bs][srow * 64 + c0] = a;
    *(f16x8*)&hl[bs][srow * 64 + c1] = b2;
  };

  const f16* WlA = WlH + ((size_t)(o0 + 16 * w + fr)) * H_ + 8 * q;

  f32x4 acc[4] = {};

  stage(0, 0);
  for (int step = 0; step < 16; ++step) {
    __syncthreads();
    if (step < 15) stage((step + 1) * 64, (step + 1) & 1);
    const int bs = step & 1;
    const int k0 = step * 64;

    f16x8 bh[4][2];
    #pragma unroll
    for (int ss = 0; ss < 4; ++ss) {
      int row = 16 * ss + fr;
      #pragma unroll
      for (int ks = 0; ks < 2; ++ks) {
        int ch = ((q + 4 * ks) ^ (row & 7)) * 8;
        bh[ss][ks] = *(const f16x8*)&hl[bs][row * 64 + ch];
      }
    }
    f16x8 ah0 = ldh8(WlA + k0);
    f16x8 ah1 = ldh8(WlA + k0 + 32);
    #pragma unroll
    for (int ss = 0; ss < 4; ++ss) {
      acc[ss] = mm16(ah0, bh[ss][0], acc[ss]);
      acc[ss] = mm16(ah1, bh[ss][1], acc[ss]);
    }
  }

  const int o = o0 + 16 * w + 4 * q;
  f32x4 bv = ld4f(bl + o);
  #pragma unroll
  for (int ss = 0; ss < 4; ++ss) {
    f32x4 v;
    #pragma unroll
    for (int c = 0; c < 4; ++c) v[c] = acc[ss][c] + bv[c];
    *(f32x4*)(out + (size_t)(r0 + 16 * ss + fr) * H_ + o) = v;
  }
}

// ---------------------------------------------------------------------------
extern "C" void kernel_launch(void* const* d_in, const int* in_sizes, int n_in,
                              void* d_out, int out_size, void* d_ws, size_t ws_size,
                              hipStream_t stream) {
  const float* x    = (const float*)d_in[0];
  const int*   mask = (const int*)d_in[1];
  const float* W    = (const float*)d_in[2];
  const float* Wl   = (const float*)d_in[3];
  const float* bl   = (const float*)d_in[4];
  float* out = (float*)d_out;

  const size_t SZ  = (size_t)B_ * NH_ * S_ * P_;      // 4,194,304
  const size_t SZW = (size_t)NH_ * 3 * H_ * P_;       // 3,145,728
  const size_t SZL = (size_t)H_ * H_;                 // 1,048,576
  const size_t SZC = (size_t)B_ * NH_ * S_;           // 65,536
  const size_t SZH = (size_t)B_ * S_ * H_;            // 4,194,304

  char* p = (char*)d_ws;
  f16*   Kh   = (f16*)p;  p += SZ * 2;
  f16*   Qh   = (f16*)p;  p += SZ * 2;
  f16*   VTh  = (f16*)p;  p += SZ * 2;
  f16*   WtH  = (f16*)p;  p += SZW * 2;
  f16*   WlH  = (f16*)p;  p += SZL * 2;
  f16*   hidh = (f16*)p;  p += SZH * 2;
  float* csuminv = (float*)p; p += SZC * 4;
  float* Cbuf    = (float*)p; p += (size_t)B_ * NH_ * P_ * 4;
  // total ~43 MB

  tw_kernel   <<<NH_ * 3 * (H_ / 64), 256, 0, stream>>>(W, WtH);
  swl_kernel  <<<(SZL / 4) / 256, 256, 0, stream>>>(Wl, WlH);
  qkv_kernel  <<<B_ * NH_ * (S_ / 64), 256, 0, stream>>>(x, WtH, Kh, Qh, VTh);
  stats_kernel<<<B_ * NH_ * (S_ / 128), 256, 0, stream>>>(Kh, Qh, csuminv);
  scale_kernel<<<B_ * NH_ * 16, 256, 0, stream>>>(VTh, csuminv, mask, Cbuf);
  av_kernel   <<<B_ * NH_ * (S_ / 64), 256, 0, stream>>>(
      Kh, Qh, VTh, Cbuf, hidh);
  final_kernel<<<(B_ * S_ / 64) * (H_ / 64), 256, 0, stream>>>(
      hidh, WlH, bl, out);
}

// Round 19
// 215.489 us; speedup vs baseline: 1.1024x; 1.0118x over previous
//
#include <hip/hip_runtime.h>

// Problem constants (B,S,H,NH,P) = (2,2048,1024,16,64)
#define B_ 2
#define S_ 2048
#define H_ 1024
#define NH_ 16
#define P_ 64

using f32x4 = __attribute__((ext_vector_type(4))) float;
using i32x4 = __attribute__((ext_vector_type(4))) int;
using f16   = _Float16;
using f16x8 = __attribute__((ext_vector_type(8))) f16;
using f16x4 = __attribute__((ext_vector_type(4))) f16;
using h16x2 = __attribute__((ext_vector_type(2))) __fp16;   // cvt_pkrtz return type

#define QSCALE 0.18033688f   // 0.125 * log2(e): exp(s/8) = exp2(s*QSCALE)

static __device__ __forceinline__ f16x8 ldh8(const f16* p) { return *(const f16x8*)p; }
static __device__ __forceinline__ f32x4 ld4f(const float* p) { return *(const f32x4*)p; }

static __device__ __forceinline__ f32x4 mm16(f16x8 a, f16x8 b, f32x4 c) {
  return __builtin_amdgcn_mfma_f32_16x16x32_f16(a, b, c, 0, 0, 0);
}

// ---------------------------------------------------------------------------
// Prep (merged): blocks [0,768): transpose W -> Wt fp16 [NH][3][P][H];
// blocks [768,1792): convert Wl -> fp16.
// ---------------------------------------------------------------------------
__global__ __launch_bounds__(256) void prep_kernel(
    const float* __restrict__ W, const float* __restrict__ Wl,
    f16* __restrict__ WtH, f16* __restrict__ WlH)
{
  __shared__ float T[64 * 65];
  const int tid = threadIdx.x;
  if (blockIdx.x < 768) {
    const int nt = blockIdx.x >> 4;
    const int h0 = (blockIdx.x & 15) * 64;
    const float* src = W + (size_t)nt * H_ * P_ + (size_t)h0 * P_;
    #pragma unroll
    for (int r = 0; r < 4; ++r) {
      int idx = tid + r * 256;
      int h = idx >> 4, p4 = (idx & 15) << 2;
      f32x4 v = ld4f(src + (size_t)h * P_ + p4);
      #pragma unroll
      for (int i = 0; i < 4; ++i) T[(p4 + i) * 65 + h] = v[i];
    }
    __syncthreads();
    f16* dh = WtH + (size_t)nt * P_ * H_;
    #pragma unroll
    for (int r = 0; r < 4; ++r) {
      int idx = tid + r * 256;
      int p = idx >> 4, h4 = (idx & 15) << 2;
      f16x4 hv;
      #pragma unroll
      for (int i = 0; i < 4; ++i) hv[i] = (f16)T[p * 65 + h4 + i];
      *(f16x4*)(dh + (size_t)p * H_ + h0 + h4) = hv;
    }
  } else {
    int idx = (blockIdx.x - 768) * 256 + tid;
    f32x4 v = ((const f32x4*)Wl)[idx];
    f16x4 h;
    #pragma unroll
    for (int i = 0; i < 4; ++i) h[i] = (f16)v[i];
    ((f16x4*)WlH)[idx] = h;
  }
}

// ---------------------------------------------------------------------------
// Kernel 1: QKV via single fp16 MFMA. x tile (64s x 64k) staged fp16 in LDS,
// double-buffered, chunk-XOR swizzled. Q pre-scaled by 0.125*log2e.
// ---------------------------------------------------------------------------
__global__ __launch_bounds__(256) void qkv_kernel(
    const float* __restrict__ x, const f16* __restrict__ WtH,
    f16* __restrict__ Kh, f16* __restrict__ Qh, f16* __restrict__ VTh)
{
  __shared__ f16 xls[2][64 * 64];

  int blk = blockIdx.x;
  const int st = blk & 31; blk >>= 5;
  const int n = blk & 15;
  const int b = blk >> 4;
  const int s0 = st * 64;
  const int tid = threadIdx.x;
  const int w = tid >> 6, lane = tid & 63, q = lane >> 4, fr = lane & 15;
  const int bn = b * NH_ + n;

  const int srow = tid >> 2, scc = tid & 3;
  const float* xsrc = x + ((size_t)b * S_ + s0 + srow) * H_ + 16 * scc;
  const int c0 = ((2 * scc) ^ (srow & 7)) * 8;
  const int c1 = ((2 * scc + 1) ^ (srow & 7)) * 8;

  auto stage = [&](int k0, int bs) {
    f32x4 v0 = ld4f(xsrc + k0),     v1 = ld4f(xsrc + k0 + 4);
    f32x4 v2 = ld4f(xsrc + k0 + 8), v3 = ld4f(xsrc + k0 + 12);
    f16x8 a, b2;
    #pragma unroll
    for (int e = 0; e < 4; ++e) {
      a[e] = (f16)v0[e];  a[e + 4] = (f16)v1[e];
      b2[e] = (f16)v2[e]; b2[e + 4] = (f16)v3[e];
    }
    *(f16x8*)&xls[bs][srow * 64 + c0] = a;
    *(f16x8*)&xls[bs][srow * 64 + c1] = b2;
  };

  const f16* WtK = WtH + ((size_t)(n * 3 + 0) * P_ + 16 * w + fr) * H_ + 8 * q;
  const f16* WtV = WtH + ((size_t)(n * 3 + 1) * P_ + 16 * w + fr) * H_ + 8 * q;
  const f16* WtQ = WtH + ((size_t)(n * 3 + 2) * P_ + 16 * w + fr) * H_ + 8 * q;

  f32x4 accK[4] = {}, accQ[4] = {}, accV[4] = {};

  stage(0, 0);
  for (int step = 0; step < 16; ++step) {
    __syncthreads();
    if (step < 15) stage((step + 1) * 64, (step + 1) & 1);
    const int bs = step & 1;
    const int k0 = step * 64;

    f16x8 xf[4][2];
    #pragma unroll
    for (int ss = 0; ss < 4; ++ss) {
      int row = 16 * ss + fr;
      #pragma unroll
      for (int ks = 0; ks < 2; ++ks) {
        int ch = ((q + 4 * ks) ^ (row & 7)) * 8;
        xf[ss][ks] = *(const f16x8*)&xls[bs][row * 64 + ch];
      }
    }
    f16x8 wk0 = ldh8(WtK + k0), wk1 = ldh8(WtK + k0 + 32);
    f16x8 wq0 = ldh8(WtQ + k0), wq1 = ldh8(WtQ + k0 + 32);
    f16x8 wv0 = ldh8(WtV + k0), wv1 = ldh8(WtV + k0 + 32);
    #pragma unroll
    for (int ss = 0; ss < 4; ++ss) {
      accK[ss] = mm16(wk0, xf[ss][0], accK[ss]);
      accK[ss] = mm16(wk1, xf[ss][1], accK[ss]);
      accQ[ss] = mm16(wq0, xf[ss][0], accQ[ss]);
      accQ[ss] = mm16(wq1, xf[ss][1], accQ[ss]);
      accV[ss] = mm16(xf[ss][0], wv0, accV[ss]);
      accV[ss] = mm16(xf[ss][1], wv1, accV[ss]);
    }
  }

  #pragma unroll
  for (int ss = 0; ss < 4; ++ss) {
    f16x4 hK, hQ;
    #pragma unroll
    for (int c = 0; c < 4; ++c) {
      hK[c] = (f16)accK[ss][c];
      hQ[c] = (f16)(accQ[ss][c] * QSCALE);
    }
    size_t off = ((size_t)bn * S_ + (s0 + 16 * ss + fr)) * P_ + 16 * w + 4 * q;
    *(f16x4*)(Kh + off) = hK;
    *(f16x4*)(Qh + off) = hQ;
  }
  #pragma unroll
  for (int ss = 0; ss < 4; ++ss) {
    f16x4 hV;
    #pragma unroll
    for (int c = 0; c < 4; ++c) hV[c] = (f16)accV[ss][c];
    size_t off = ((size_t)bn * P_ + (16 * w + fr)) * S_ + s0 + 16 * ss + 4 * q;
    *(f16x4*)(VTh + off) = hV;
  }
}

// ---------------------------------------------------------------------------
// Kernel 2: column sum-exp2, j-tile 128 (grid 512), barrier-free main loop.
// FUSED epilogue: V' = mask ? zinv*V : 0 (in-place on VT), vectorized mask
// loads; atomic partial C[bn][p] += (1/S)*sum of masked-out V for this tile.
// ---------------------------------------------------------------------------
__global__ __launch_bounds__(256) void stats_kernel(
    const f16* __restrict__ Kh, const f16* __restrict__ Qh,
    f16* __restrict__ VT, const int* __restrict__ mask,
    float* __restrict__ Cbuf)
{
  __shared__ float zbuf[2 * 128];
  const int tid = threadIdx.x;
  const int bid = blockIdx.x;
  const int j0 = (bid & 15) * 128;
  const int bn = bid >> 4;
  const int w = tid >> 6, lane = tid & 63, q = lane >> 4, fr = lane & 15;
  const int jb = 64 * (w & 1), ih = w >> 1, ib0 = 32 * ih;

  f16x8 qf[4][2];
  #pragma unroll
  for (int jt = 0; jt < 4; ++jt)
    #pragma unroll
    for (int ks = 0; ks < 2; ++ks)
      qf[jt][ks] = ldh8(Qh + ((size_t)bn * S_ + (j0 + jb + 16 * jt + fr)) * P_ + 8 * q + 32 * ks);

  f32x4 z[4] = {};
  f16x8 kA[2][2], kB[2][2];

  auto loadK = [&](f16x8 (&kf)[2][2], int i0) {
    #pragma unroll
    for (int it = 0; it < 2; ++it)
      #pragma unroll
      for (int ks = 0; ks < 2; ++ks)
        kf[it][ks] = ldh8(Kh + ((size_t)bn * S_ + (i0 + ib0 + 16 * it + fr)) * P_ + 8 * q + 32 * ks);
  };
  auto step = [&](f16x8 (&kf)[2][2]) {
    f32x4 sc[4][2] = {};
    __builtin_amdgcn_s_setprio(1);
    #pragma unroll
    for (int ks = 0; ks < 2; ++ks)
      #pragma unroll
      for (int jt = 0; jt < 4; ++jt)
        #pragma unroll
        for (int it = 0; it < 2; ++it)
          sc[jt][it] = mm16(qf[jt][ks], kf[it][ks], sc[jt][it]);
    __builtin_amdgcn_s_setprio(0);
    #pragma unroll
    for (int jt = 0; jt < 4; ++jt)
      #pragma unroll
      for (int c = 0; c < 4; ++c)
        z[jt][c] += exp2f(sc[jt][0][c]) + exp2f(sc[jt][1][c]);
  };

  loadK(kA, 0);
  for (int i0 = 0; i0 < S_; i0 += 128) {
    loadK(kB, i0 + 64);
    step(kA);
    loadK(kA, (i0 + 128) & (S_ - 1));
    step(kB);
  }

  #pragma unroll
  for (int msk = 1; msk <= 8; msk <<= 1)
    #pragma unroll
    for (int jt = 0; jt < 4; ++jt)
      #pragma unroll
      for (int c = 0; c < 4; ++c)
        z[jt][c] += __shfl_xor(z[jt][c], msk, 64);

  if (fr == 0) {
    #pragma unroll
    for (int jt = 0; jt < 4; ++jt)
      *(f32x4*)&zbuf[ih * 128 + jb + 16 * jt + 4 * q] = z[jt];
  }
  __syncthreads();
  if (tid < 128)
    zbuf[tid] = 1.0f / (zbuf[tid] + zbuf[128 + tid]);   // zinv for local j
  __syncthreads();

  // ---- fused V-scale + C partial over this j-tile ----
  const int sp = tid >> 2;             // p row 0..63
  const int jc = (tid & 3) * 32;       // j chunk within tile
  f16* vrow = VT + ((size_t)bn * P_ + sp) * S_ + j0 + jc;
  const int* mr = mask + (size_t)(bn >> 4) * S_ + j0 + jc;
  float acc = 0.0f;
  #pragma unroll
  for (int k = 0; k < 4; ++k) {
    f16x8 v = *(const f16x8*)(vrow + 8 * k);
    i32x4 m0 = *(const i32x4*)(mr + 8 * k);
    i32x4 m1 = *(const i32x4*)(mr + 8 * k + 4);
    f16x8 o;
    #pragma unroll
    for (int e = 0; e < 4; ++e) {
      float fv = (float)v[e];
      if (m0[e] != 0) o[e] = (f16)(fv * zbuf[jc + 8 * k + e]);
      else { o[e] = (f16)0.0f; acc += fv; }
      float fv2 = (float)v[e + 4];
      if (m1[e] != 0) o[e + 4] = (f16)(fv2 * zbuf[jc + 8 * k + e + 4]);
      else { o[e + 4] = (f16)0.0f; acc += fv2; }
    }
    *(f16x8*)(vrow + 8 * k) = o;
  }
  acc += __shfl_xor(acc, 1, 64);
  acc += __shfl_xor(acc, 2, 64);
  if ((tid & 3) == 0) atomicAdd(&Cbuf[bn * P_ + sp], acc * (1.0f / S_));
}

// ---------------------------------------------------------------------------
// Kernel 3: AV pass, barrier-free hot loop, i-tile 64, grid 1024, 4 waves.
// Wave w owns j-slices {T*128 + w*32}, T=0..15. Software-pipelined it-chains.
// ---------------------------------------------------------------------------
__global__ __launch_bounds__(256) void av_kernel(
    const f16* __restrict__ Kh, const f16* __restrict__ Qh,
    const f16* __restrict__ VT, const float* __restrict__ Cbuf,
    f16* __restrict__ hidh)
{
  __shared__ __align__(16) char smem[18432];  // max(4*64*36*2, 64*68*4)
  const int tid = threadIdx.x;
  const int bid = blockIdx.x;
  const int i0 = (bid & 31) * 64;
  const int bn = bid >> 5;
  const int b = bn >> 4, n = bn & 15;
  const int w = tid >> 6, lane = tid & 63, q = lane >> 4, fr = lane & 15;
  f16* ew = (f16*)smem + w * (64 * 36);

  f16x8 kf[4][2];
  #pragma unroll
  for (int it = 0; it < 4; ++it)
    #pragma unroll
    for (int ks = 0; ks < 2; ++ks)
      kf[it][ks] = ldh8(Kh + ((size_t)bn * S_ + (i0 + 16 * it + fr)) * P_ + 8 * q + 32 * ks);

  const f16* qp  = Qh + ((size_t)bn * S_ + (w * 32 + fr)) * P_ + 8 * q;
  const f16* vp0 = VT + ((size_t)bn * P_ + fr) * S_ + w * 32 + 8 * q;
  const f16* vp1 = vp0 + (size_t)16 * S_;
  const f16* vp2 = vp0 + (size_t)32 * S_;
  const f16* vp3 = vp0 + (size_t)48 * S_;

  f32x4 opv[4][4] = {};   // [pt][it]: p = 16pt+4q+c, i = 16it+fr

  for (int T = 0; T < 16; ++T) {
    f16x8 aq00 = ldh8(qp);
    f16x8 aq01 = ldh8(qp + 32);
    f16x8 aq10 = ldh8(qp + 1024);
    f16x8 aq11 = ldh8(qp + 1056);
    f16x8 va0 = ldh8(vp0), va1 = ldh8(vp1), va2 = ldh8(vp2), va3 = ldh8(vp3);
    qp += 128 * 64;
    vp0 += 128; vp1 += 128; vp2 += 128; vp3 += 128;

    #pragma unroll
    for (int it = 0; it < 4; ++it) {
      {
        f32x4 s0 = {}, s1 = {};
        s0 = mm16(aq00, kf[it][0], s0);
        s0 = mm16(aq01, kf[it][1], s0);
        s1 = mm16(aq10, kf[it][0], s1);
        s1 = mm16(aq11, kf[it][1], s1);
        union { f16x4 v; h16x2 h[2]; } e0, e1;
        e0.h[0] = __builtin_amdgcn_cvt_pkrtz(exp2f(s0[0]), exp2f(s0[1]));
        e0.h[1] = __builtin_amdgcn_cvt_pkrtz(exp2f(s0[2]), exp2f(s0[3]));
        e1.h[0] = __builtin_amdgcn_cvt_pkrtz(exp2f(s1[0]), exp2f(s1[1]));
        e1.h[1] = __builtin_amdgcn_cvt_pkrtz(exp2f(s1[2]), exp2f(s1[3]));
        *(f16x4*)(ew + (16 * it + fr) * 36 + 4 * q)      = e0.v;
        *(f16x4*)(ew + (16 * it + fr) * 36 + 16 + 4 * q) = e1.v;
      }
      if (it > 0) {
        const int pv = it - 1;
        f16x8 ef = *(const f16x8*)(ew + (16 * pv + fr) * 36 + 8 * q);
        opv[0][pv] = mm16(va0, ef, opv[0][pv]);
        opv[1][pv] = mm16(va1, ef, opv[1][pv]);
        opv[2][pv] = mm16(va2, ef, opv[2][pv]);
        opv[3][pv] = mm16(va3, ef, opv[3][pv]);
      }
    }
    {
      f16x8 ef = *(const f16x8*)(ew + (16 * 3 + fr) * 36 + 8 * q);
      opv[0][3] = mm16(va0, ef, opv[0][3]);
      opv[1][3] = mm16(va1, ef, opv[1][3]);
      opv[2][3] = mm16(va2, ef, opv[2][3]);
      opv[3][3] = mm16(va3, ef, opv[3][3]);
    }
  }

  // ---- epilogue: reduce 4 wave-partials via LDS (reuses smem as f32 acc) ----
  float* accl = (float*)smem;   // [64][68] pitch 68
  #pragma unroll
  for (int r = 0; r < 4; ++r) {
    __syncthreads();
    if (w == r) {
      #pragma unroll
      for (int it = 0; it < 4; ++it)
        #pragma unroll
        for (int pt = 0; pt < 4; ++pt) {
          float* a = &accl[(16 * it + fr) * 68 + 16 * pt + 4 * q];
          if (r == 0) *(f32x4*)a = opv[pt][it];
          else {
            f32x4 old = *(const f32x4*)a;
            #pragma unroll
            for (int c = 0; c < 4; ++c) old[c] += opv[pt][it][c];
            *(f32x4*)a = old;
          }
        }
    }
  }
  __syncthreads();

  const int ti = tid >> 2;
  const int tp = (tid & 3) << 4;
  const float* cb = Cbuf + bn * P_ + tp;
  f16* dst = hidh + ((size_t)b * S_ + (i0 + ti)) * H_ + n * P_ + tp;
  #pragma unroll
  for (int h = 0; h < 2; ++h) {
    f32x4 a0 = *(const f32x4*)&accl[ti * 68 + tp + 8 * h];
    f32x4 a1 = *(const f32x4*)&accl[ti * 68 + tp + 8 * h + 4];
    f32x4 c0 = ld4f(cb + 8 * h);
    f32x4 c1 = ld4f(cb + 8 * h + 4);
    f16x8 o;
    #pragma unroll
    for (int e = 0; e < 4; ++e) {
      o[e]     = (f16)(a0[e] + c0[e]);
      o[e + 4] = (f16)(a1[e] + c1[e]);
    }
    *(f16x8*)(dst + 8 * h) = o;
  }
}

// ---------------------------------------------------------------------------
// Kernel 4: out = hid @ Wl.T + bl via fp16 MFMA. BK=64, hid tile staged in
// LDS, double-buffered, chunk-XOR swizzled.
// ---------------------------------------------------------------------------
__global__ __launch_bounds__(256) void final_kernel(
    const f16* __restrict__ hidh, const f16* __restrict__ WlH,
    const float* __restrict__ bl, float* __restrict__ out)
{
  __shared__ f16 hl[2][64 * 64];
  const int tid = threadIdx.x;
  const int ot = blockIdx.x & 15;
  const int rt = blockIdx.x >> 4;
  const int r0 = rt * 64, o0 = ot * 64;
  const int w = tid >> 6, lane = tid & 63, q = lane >> 4, fr = lane & 15;

  const int srow = tid >> 2, scc = tid & 3;
  const f16* hsrc = hidh + (size_t)(r0 + srow) * H_ + 16 * scc;
  const int c0 = ((2 * scc) ^ (srow & 7)) * 8;
  const int c1 = ((2 * scc + 1) ^ (srow & 7)) * 8;

  auto stage = [&](int k0, int bs) {
    f16x8 a = ldh8(hsrc + k0);
    f16x8 b2 = ldh8(hsrc + k0 + 8);
    *(f16x8*)&hl[bs][srow * 64 + c0] = a;
    *(f16x8*)&hl[bs][srow * 64 + c1] = b2;
  };

  const f16* WlA = WlH + ((size_t)(o0 + 16 * w + fr)) * H_ + 8 * q;

  f32x4 acc[4] = {};

  stage(0, 0);
  for (int step = 0; step < 16; ++step) {
    __syncthreads();
    if (step < 15) stage((step + 1) * 64, (step + 1) & 1);
    const int bs = step & 1;
    const int k0 = step * 64;

    f16x8 bh[4][2];
    #pragma unroll
    for (int ss = 0; ss < 4; ++ss) {
      int row = 16 * ss + fr;
      #pragma unroll
      for (int ks = 0; ks < 2; ++ks) {
        int ch = ((q + 4 * ks) ^ (row & 7)) * 8;
        bh[ss][ks] = *(const f16x8*)&hl[bs][row * 64 + ch];
      }
    }
    f16x8 ah0 = ldh8(WlA + k0);
    f16x8 ah1 = ldh8(WlA + k0 + 32);
    #pragma unroll
    for (int ss = 0; ss < 4; ++ss) {
      acc[ss] = mm16(ah0, bh[ss][0], acc[ss]);
      acc[ss] = mm16(ah1, bh[ss][1], acc[ss]);
    }
  }

  const int o = o0 + 16 * w + 4 * q;
  f32x4 bv = ld4f(bl + o);
  #pragma unroll
  for (int ss = 0; ss < 4; ++ss) {
    f32x4 v;
    #pragma unroll
    for (int c = 0; c < 4; ++c) v[c] = acc[ss][c] + bv[c];
    *(f32x4*)(out + (size_t)(r0 + 16 * ss + fr) * H_ + o) = v;
  }
}

// ---------------------------------------------------------------------------
extern "C" void kernel_launch(void* const* d_in, const int* in_sizes, int n_in,
                              void* d_out, int out_size, void* d_ws, size_t ws_size,
                              hipStream_t stream) {
  const float* x    = (const float*)d_in[0];
  const int*   mask = (const int*)d_in[1];
  const float* W    = (const float*)d_in[2];
  const float* Wl   = (const float*)d_in[3];
  const float* bl   = (const float*)d_in[4];
  float* out = (float*)d_out;

  const size_t SZ  = (size_t)B_ * NH_ * S_ * P_;      // 4,194,304
  const size_t SZW = (size_t)NH_ * 3 * H_ * P_;       // 3,145,728
  const size_t SZL = (size_t)H_ * H_;                 // 1,048,576
  const size_t SZH = (size_t)B_ * S_ * H_;            // 4,194,304

  char* p = (char*)d_ws;
  f16*   Kh   = (f16*)p;  p += SZ * 2;
  f16*   Qh   = (f16*)p;  p += SZ * 2;
  f16*   VTh  = (f16*)p;  p += SZ * 2;
  f16*   WtH  = (f16*)p;  p += SZW * 2;
  f16*   WlH  = (f16*)p;  p += SZL * 2;
  f16*   hidh = (f16*)p;  p += SZH * 2;
  float* Cbuf = (float*)p; p += (size_t)B_ * NH_ * P_ * 4;
  // total ~42.8 MB

  prep_kernel <<<1792, 256, 0, stream>>>(W, Wl, WtH, WlH);
  qkv_kernel  <<<B_ * NH_ * (S_ / 64), 256, 0, stream>>>(x, WtH, Kh, Qh, VTh);
  hipMemsetAsync(Cbuf, 0, (size_t)B_ * NH_ * P_ * 4, stream);
  stats_kernel<<<B_ * NH_ * (S_ / 128), 256, 0, stream>>>(
      Kh, Qh, VTh, mask, Cbuf);
  av_kernel   <<<B_ * NH_ * (S_ / 64), 256, 0, stream>>>(
      Kh, Qh, VTh, Cbuf, hidh);
  final_kernel<<<(B_ * S_ / 64) * (H_ / 64), 256, 0, stream>>>(
      hidh, WlH, bl, out);
}

// Round 20
// 214.315 us; speedup vs baseline: 1.1085x; 1.0055x over previous
//
#include <hip/hip_runtime.h>

// Problem constants (B,S,H,NH,P) = (2,2048,1024,16,64)
#define B_ 2
#define S_ 2048
#define H_ 1024
#define NH_ 16
#define P_ 64

using f32x4 = __attribute__((ext_vector_type(4))) float;
using i32x4 = __attribute__((ext_vector_type(4))) int;
using f16   = _Float16;
using f16x8 = __attribute__((ext_vector_type(8))) f16;
using f16x4 = __attribute__((ext_vector_type(4))) f16;
using h16x2 = __attribute__((ext_vector_type(2))) __fp16;   // cvt_pkrtz return type

#define QSCALE 0.18033688f   // 0.125 * log2(e): exp(s/8) = exp2(s*QSCALE)

static __device__ __forceinline__ f16x8 ldh8(const f16* p) { return *(const f16x8*)p; }
static __device__ __forceinline__ f32x4 ld4f(const float* p) { return *(const f32x4*)p; }

static __device__ __forceinline__ f32x4 mm16(f16x8 a, f16x8 b, f32x4 c) {
  return __builtin_amdgcn_mfma_f32_16x16x32_f16(a, b, c, 0, 0, 0);
}

// ---------------------------------------------------------------------------
// Prep (merged): blocks [0,768): transpose W -> Wt fp16 [NH][3][P][H];
// blocks [768,1792): convert Wl -> fp16.
// ---------------------------------------------------------------------------
__global__ __launch_bounds__(256) void prep_kernel(
    const float* __restrict__ W, const float* __restrict__ Wl,
    f16* __restrict__ WtH, f16* __restrict__ WlH)
{
  __shared__ float T[64 * 65];
  const int tid = threadIdx.x;
  if (blockIdx.x < 768) {
    const int nt = blockIdx.x >> 4;
    const int h0 = (blockIdx.x & 15) * 64;
    const float* src = W + (size_t)nt * H_ * P_ + (size_t)h0 * P_;
    #pragma unroll
    for (int r = 0; r < 4; ++r) {
      int idx = tid + r * 256;
      int h = idx >> 4, p4 = (idx & 15) << 2;
      f32x4 v = ld4f(src + (size_t)h * P_ + p4);
      #pragma unroll
      for (int i = 0; i < 4; ++i) T[(p4 + i) * 65 + h] = v[i];
    }
    __syncthreads();
    f16* dh = WtH + (size_t)nt * P_ * H_;
    #pragma unroll
    for (int r = 0; r < 4; ++r) {
      int idx = tid + r * 256;
      int p = idx >> 4, h4 = (idx & 15) << 2;
      f16x4 hv;
      #pragma unroll
      for (int i = 0; i < 4; ++i) hv[i] = (f16)T[p * 65 + h4 + i];
      *(f16x4*)(dh + (size_t)p * H_ + h0 + h4) = hv;
    }
  } else {
    int idx = (blockIdx.x - 768) * 256 + tid;
    f32x4 v = ((const f32x4*)Wl)[idx];
    f16x4 h;
    #pragma unroll
    for (int i = 0; i < 4; ++i) h[i] = (f16)v[i];
    ((f16x4*)WlH)[idx] = h;
  }
}

// ---------------------------------------------------------------------------
// Kernel 1: QKV via single fp16 MFMA. x tile (64s x 64k) staged fp16 in LDS,
// double-buffered, chunk-XOR swizzled. Q pre-scaled by 0.125*log2e.
// ---------------------------------------------------------------------------
__global__ __launch_bounds__(256) void qkv_kernel(
    const float* __restrict__ x, const f16* __restrict__ WtH,
    f16* __restrict__ Kh, f16* __restrict__ Qh, f16* __restrict__ VTh)
{
  __shared__ f16 xls[2][64 * 64];

  int blk = blockIdx.x;
  const int st = blk & 31; blk >>= 5;
  const int n = blk & 15;
  const int b = blk >> 4;
  const int s0 = st * 64;
  const int tid = threadIdx.x;
  const int w = tid >> 6, lane = tid & 63, q = lane >> 4, fr = lane & 15;
  const int bn = b * NH_ + n;

  const int srow = tid >> 2, scc = tid & 3;
  const float* xsrc = x + ((size_t)b * S_ + s0 + srow) * H_ + 16 * scc;
  const int c0 = ((2 * scc) ^ (srow & 7)) * 8;
  const int c1 = ((2 * scc + 1) ^ (srow & 7)) * 8;

  auto stage = [&](int k0, int bs) {
    f32x4 v0 = ld4f(xsrc + k0),     v1 = ld4f(xsrc + k0 + 4);
    f32x4 v2 = ld4f(xsrc + k0 + 8), v3 = ld4f(xsrc + k0 + 12);
    f16x8 a, b2;
    #pragma unroll
    for (int e = 0; e < 4; ++e) {
      a[e] = (f16)v0[e];  a[e + 4] = (f16)v1[e];
      b2[e] = (f16)v2[e]; b2[e + 4] = (f16)v3[e];
    }
    *(f16x8*)&xls[bs][srow * 64 + c0] = a;
    *(f16x8*)&xls[bs][srow * 64 + c1] = b2;
  };

  const f16* WtK = WtH + ((size_t)(n * 3 + 0) * P_ + 16 * w + fr) * H_ + 8 * q;
  const f16* WtV = WtH + ((size_t)(n * 3 + 1) * P_ + 16 * w + fr) * H_ + 8 * q;
  const f16* WtQ = WtH + ((size_t)(n * 3 + 2) * P_ + 16 * w + fr) * H_ + 8 * q;

  f32x4 accK[4] = {}, accQ[4] = {}, accV[4] = {};

  stage(0, 0);
  for (int step = 0; step < 16; ++step) {
    __syncthreads();
    if (step < 15) stage((step + 1) * 64, (step + 1) & 1);
    const int bs = step & 1;
    const int k0 = step * 64;

    f16x8 xf[4][2];
    #pragma unroll
    for (int ss = 0; ss < 4; ++ss) {
      int row = 16 * ss + fr;
      #pragma unroll
      for (int ks = 0; ks < 2; ++ks) {
        int ch = ((q + 4 * ks) ^ (row & 7)) * 8;
        xf[ss][ks] = *(const f16x8*)&xls[bs][row * 64 + ch];
      }
    }
    f16x8 wk0 = ldh8(WtK + k0), wk1 = ldh8(WtK + k0 + 32);
    f16x8 wq0 = ldh8(WtQ + k0), wq1 = ldh8(WtQ + k0 + 32);
    f16x8 wv0 = ldh8(WtV + k0), wv1 = ldh8(WtV + k0 + 32);
    #pragma unroll
    for (int ss = 0; ss < 4; ++ss) {
      accK[ss] = mm16(wk0, xf[ss][0], accK[ss]);
      accK[ss] = mm16(wk1, xf[ss][1], accK[ss]);
      accQ[ss] = mm16(wq0, xf[ss][0], accQ[ss]);
      accQ[ss] = mm16(wq1, xf[ss][1], accQ[ss]);
      accV[ss] = mm16(xf[ss][0], wv0, accV[ss]);
      accV[ss] = mm16(xf[ss][1], wv1, accV[ss]);
    }
  }

  #pragma unroll
  for (int ss = 0; ss < 4; ++ss) {
    f16x4 hK, hQ;
    #pragma unroll
    for (int c = 0; c < 4; ++c) {
      hK[c] = (f16)accK[ss][c];
      hQ[c] = (f16)(accQ[ss][c] * QSCALE);
    }
    size_t off = ((size_t)bn * S_ + (s0 + 16 * ss + fr)) * P_ + 16 * w + 4 * q;
    *(f16x4*)(Kh + off) = hK;
    *(f16x4*)(Qh + off) = hQ;
  }
  #pragma unroll
  for (int ss = 0; ss < 4; ++ss) {
    f16x4 hV;
    #pragma unroll
    for (int c = 0; c < 4; ++c) hV[c] = (f16)accV[ss][c];
    size_t off = ((size_t)bn * P_ + (16 * w + fr)) * S_ + s0 + 16 * ss + 4 * q;
    *(f16x4*)(VTh + off) = hV;
  }
}

// ---------------------------------------------------------------------------
// Kernel 2: column sum-exp2, j-tile 128 (grid 512), barrier-free main loop.
// FUSED epilogue: V' = mask ? zinv*V : 0 written back PERMUTED within each
// 32-col chunk (physical p <- logical l(p)=4*(p>>3)+(p&3)+((p&4)?16:0)),
// matching av's register-resident E k-mapping. Atomic C partial.
// ---------------------------------------------------------------------------
__global__ __launch_bounds__(256) void stats_kernel(
    const f16* __restrict__ Kh, const f16* __restrict__ Qh,
    f16* __restrict__ VT, const int* __restrict__ mask,
    float* __restrict__ Cbuf)
{
  __shared__ float zbuf[2 * 128];
  const int tid = threadIdx.x;
  const int bid = blockIdx.x;
  const int j0 = (bid & 15) * 128;
  const int bn = bid >> 4;
  const int w = tid >> 6, lane = tid & 63, q = lane >> 4, fr = lane & 15;
  const int jb = 64 * (w & 1), ih = w >> 1, ib0 = 32 * ih;

  f16x8 qf[4][2];
  #pragma unroll
  for (int jt = 0; jt < 4; ++jt)
    #pragma unroll
    for (int ks = 0; ks < 2; ++ks)
      qf[jt][ks] = ldh8(Qh + ((size_t)bn * S_ + (j0 + jb + 16 * jt + fr)) * P_ + 8 * q + 32 * ks);

  f32x4 z[4] = {};
  f16x8 kA[2][2], kB[2][2];

  auto loadK = [&](f16x8 (&kf)[2][2], int i0) {
    #pragma unroll
    for (int it = 0; it < 2; ++it)
      #pragma unroll
      for (int ks = 0; ks < 2; ++ks)
        kf[it][ks] = ldh8(Kh + ((size_t)bn * S_ + (i0 + ib0 + 16 * it + fr)) * P_ + 8 * q + 32 * ks);
  };
  auto step = [&](f16x8 (&kf)[2][2]) {
    f32x4 sc[4][2] = {};
    __builtin_amdgcn_s_setprio(1);
    #pragma unroll
    for (int ks = 0; ks < 2; ++ks)
      #pragma unroll
      for (int jt = 0; jt < 4; ++jt)
        #pragma unroll
        for (int it = 0; it < 2; ++it)
          sc[jt][it] = mm16(qf[jt][ks], kf[it][ks], sc[jt][it]);
    __builtin_amdgcn_s_setprio(0);
    #pragma unroll
    for (int jt = 0; jt < 4; ++jt)
      #pragma unroll
      for (int c = 0; c < 4; ++c)
        z[jt][c] += exp2f(sc[jt][0][c]) + exp2f(sc[jt][1][c]);
  };

  loadK(kA, 0);
  for (int i0 = 0; i0 < S_; i0 += 128) {
    loadK(kB, i0 + 64);
    step(kA);
    loadK(kA, (i0 + 128) & (S_ - 1));
    step(kB);
  }

  #pragma unroll
  for (int msk = 1; msk <= 8; msk <<= 1)
    #pragma unroll
    for (int jt = 0; jt < 4; ++jt)
      #pragma unroll
      for (int c = 0; c < 4; ++c)
        z[jt][c] += __shfl_xor(z[jt][c], msk, 64);

  if (fr == 0) {
    #pragma unroll
    for (int jt = 0; jt < 4; ++jt)
      *(f32x4*)&zbuf[ih * 128 + jb + 16 * jt + 4 * q] = z[jt];
  }
  __syncthreads();
  if (tid < 128)
    zbuf[tid] = 1.0f / (zbuf[tid] + zbuf[128 + tid]);   // zinv for local j
  __syncthreads();

  // ---- fused V-scale + permuted write + C partial over this j-tile ----
  const int sp = tid >> 2;             // p row 0..63
  const int jc = (tid & 3) * 32;       // 32-col chunk within tile
  f16* vrow = VT + ((size_t)bn * P_ + sp) * S_ + j0 + jc;
  const int* mr = mask + (size_t)(bn >> 4) * S_ + j0 + jc;
  float acc = 0.0f;
  f16 lo[32];                          // logical-indexed scaled values
  #pragma unroll
  for (int k = 0; k < 4; ++k) {
    f16x8 v = *(const f16x8*)(vrow + 8 * k);
    i32x4 m0 = *(const i32x4*)(mr + 8 * k);
    i32x4 m1 = *(const i32x4*)(mr + 8 * k + 4);
    #pragma unroll
    for (int e = 0; e < 4; ++e) {
      float fv = (float)v[e];
      if (m0[e] != 0) lo[8 * k + e] = (f16)(fv * zbuf[jc + 8 * k + e]);
      else { lo[8 * k + e] = (f16)0.0f; acc += fv; }
      float fv2 = (float)v[e + 4];
      if (m1[e] != 0) lo[8 * k + e + 4] = (f16)(fv2 * zbuf[jc + 8 * k + e + 4]);
      else { lo[8 * k + e + 4] = (f16)0.0f; acc += fv2; }
    }
  }
  // permuted write: physical p holds logical l(p) = 4*(p>>3)+(p&3)+((p&4)?16:0)
  #pragma unroll
  for (int k2 = 0; k2 < 4; ++k2) {
    f16x8 o;
    #pragma unroll
    for (int e = 0; e < 8; ++e) {
      const int l = 4 * k2 + (e & 3) + ((e & 4) ? 16 : 0);
      o[e] = lo[l];
    }
    *(f16x8*)(vrow + 8 * k2) = o;
  }
  acc += __shfl_xor(acc, 1, 64);
  acc += __shfl_xor(acc, 2, 64);
  if ((tid & 3) == 0) atomicAdd(&Cbuf[bn * P_ + sp], acc * (1.0f / S_));
}

// ---------------------------------------------------------------------------
// Kernel 3: AV pass, fully register-resident hot loop (no LDS, no barriers,
// no cross-lane). i-tile 64, grid 1024, 4 waves; wave w owns j {T*128+w*32}.
// E built in-register from pkrtz (physical k = 8q+e <-> logical l(k));
// VT pre-permuted by stats so contiguous va loads match. 16 QK + 16 PV mfma
// + 32 exp2 per step.
// ---------------------------------------------------------------------------
__global__ __launch_bounds__(256) void av_kernel(
    const f16* __restrict__ Kh, const f16* __restrict__ Qh,
    const f16* __restrict__ VT, const float* __restrict__ Cbuf,
    f16* __restrict__ hidh)
{
  __shared__ __align__(16) float accl[64 * 68];
  const int tid = threadIdx.x;
  const int bid = blockIdx.x;
  const int i0 = (bid & 31) * 64;
  const int bn = bid >> 5;
  const int b = bn >> 4, n = bn & 15;
  const int w = tid >> 6, lane = tid & 63, q = lane >> 4, fr = lane & 15;

  f16x8 kf[4][2];
  #pragma unroll
  for (int it = 0; it < 4; ++it)
    #pragma unroll
    for (int ks = 0; ks < 2; ++ks)
      kf[it][ks] = ldh8(Kh + ((size_t)bn * S_ + (i0 + 16 * it + fr)) * P_ + 8 * q + 32 * ks);

  const f16* qp  = Qh + ((size_t)bn * S_ + (w * 32 + fr)) * P_ + 8 * q;
  const f16* vp0 = VT + ((size_t)bn * P_ + fr) * S_ + w * 32 + 8 * q;
  const f16* vp1 = vp0 + (size_t)16 * S_;
  const f16* vp2 = vp0 + (size_t)32 * S_;
  const f16* vp3 = vp0 + (size_t)48 * S_;

  f32x4 opv[4][4] = {};   // [pt][it]: p = 16pt+4q+c, i = 16it+fr

  for (int T = 0; T < 16; ++T) {
    f16x8 aq00 = ldh8(qp);           // jt=0 ks=0
    f16x8 aq01 = ldh8(qp + 32);      // jt=0 ks=1
    f16x8 aq10 = ldh8(qp + 1024);    // jt=1 ks=0
    f16x8 aq11 = ldh8(qp + 1056);    // jt=1 ks=1
    f16x8 va0 = ldh8(vp0), va1 = ldh8(vp1), va2 = ldh8(vp2), va3 = ldh8(vp3);
    qp += 128 * 64;
    vp0 += 128; vp1 += 128; vp2 += 128; vp3 += 128;

    #pragma unroll
    for (int it = 0; it < 4; ++it) {
      f32x4 s0 = {}, s1 = {};
      s0 = mm16(aq00, kf[it][0], s0);
      s0 = mm16(aq01, kf[it][1], s0);
      s1 = mm16(aq10, kf[it][0], s1);
      s1 = mm16(aq11, kf[it][1], s1);
      // register-resident E: physical k=8q+e holds logical j
      // {4q+c (e<4), 16+4q+c (e>=4)} — matches VT's permutation.
      union { f16x8 v8; h16x2 h[4]; } ef;
      ef.h[0] = __builtin_amdgcn_cvt_pkrtz(exp2f(s0[0]), exp2f(s0[1]));
      ef.h[1] = __builtin_amdgcn_cvt_pkrtz(exp2f(s0[2]), exp2f(s0[3]));
      ef.h[2] = __builtin_amdgcn_cvt_pkrtz(exp2f(s1[0]), exp2f(s1[1]));
      ef.h[3] = __builtin_amdgcn_cvt_pkrtz(exp2f(s1[2]), exp2f(s1[3]));
      opv[0][it] = mm16(va0, ef.v8, opv[0][it]);
      opv[1][it] = mm16(va1, ef.v8, opv[1][it]);
      opv[2][it] = mm16(va2, ef.v8, opv[2][it]);
      opv[3][it] = mm16(va3, ef.v8, opv[3][it]);
    }
  }

  // ---- epilogue: reduce 4 wave-partials via LDS ----
  #pragma unroll
  for (int r = 0; r < 4; ++r) {
    __syncthreads();
    if (w == r) {
      #pragma unroll
      for (int it = 0; it < 4; ++it)
        #pragma unroll
        for (int pt = 0; pt < 4; ++pt) {
          float* a = &accl[(16 * it + fr) * 68 + 16 * pt + 4 * q];
          if (r == 0) *(f32x4*)a = opv[pt][it];
          else {
            f32x4 old = *(const f32x4*)a;
            #pragma unroll
            for (int c = 0; c < 4; ++c) old[c] += opv[pt][it][c];
            *(f32x4*)a = old;
          }
        }
    }
  }
  __syncthreads();

  const int ti = tid >> 2;
  const int tp = (tid & 3) << 4;
  const float* cb = Cbuf + bn * P_ + tp;
  f16* dst = hidh + ((size_t)b * S_ + (i0 + ti)) * H_ + n * P_ + tp;
  #pragma unroll
  for (int h = 0; h < 2; ++h) {
    f32x4 a0 = *(const f32x4*)&accl[ti * 68 + tp + 8 * h];
    f32x4 a1 = *(const f32x4*)&accl[ti * 68 + tp + 8 * h + 4];
    f32x4 c0 = ld4f(cb + 8 * h);
    f32x4 c1 = ld4f(cb + 8 * h + 4);
    f16x8 o;
    #pragma unroll
    for (int e = 0; e < 4; ++e) {
      o[e]     = (f16)(a0[e] + c0[e]);
      o[e + 4] = (f16)(a1[e] + c1[e]);
    }
    *(f16x8*)(dst + 8 * h) = o;
  }
}

// ---------------------------------------------------------------------------
// Kernel 4: out = hid @ Wl.T + bl via fp16 MFMA. BK=64, hid tile staged in
// LDS, double-buffered, chunk-XOR swizzled.
// ---------------------------------------------------------------------------
__global__ __launch_bounds__(256) void final_kernel(
    const f16* __restrict__ hidh, const f16* __restrict__ WlH,
    const float* __restrict__ bl, float* __restrict__ out)
{
  __shared__ f16 hl[2][64 * 64];
  const int tid = threadIdx.x;
  const int ot = blockIdx.x & 15;
  const int rt = blockIdx.x >> 4;
  const int r0 = rt * 64, o0 = ot * 64;
  const int w = tid >> 6, lane = tid & 63, q = lane >> 4, fr = lane & 15;

  const int srow = tid >> 2, scc = tid & 3;
  const f16* hsrc = hidh + (size_t)(r0 + srow) * H_ + 16 * scc;
  const int c0 = ((2 * scc) ^ (srow & 7)) * 8;
  const int c1 = ((2 * scc + 1) ^ (srow & 7)) * 8;

  auto stage = [&](int k0, int bs) {
    f16x8 a = ldh8(hsrc + k0);
    f16x8 b2 = ldh8(hsrc + k0 + 8);
    *(f16x8*)&hl[bs][srow * 64 + c0] = a;
    *(f16x8*)&hl[bs][srow * 64 + c1] = b2;
  };

  const f16* WlA = WlH + ((size_t)(o0 + 16 * w + fr)) * H_ + 8 * q;

  f32x4 acc[4] = {};

  stage(0, 0);
  for (int step = 0; step < 16; ++step) {
    __syncthreads();
    if (step < 15) stage((step + 1) * 64, (step + 1) & 1);
    const int bs = step & 1;
    const int k0 = step * 64;

    f16x8 bh[4][2];
    #pragma unroll
    for (int ss = 0; ss < 4; ++ss) {
      int row = 16 * ss + fr;
      #pragma unroll
      for (int ks = 0; ks < 2; ++ks) {
        int ch = ((q + 4 * ks) ^ (row & 7)) * 8;
        bh[ss][ks] = *(const f16x8*)&hl[bs][row * 64 + ch];
      }
    }
    f16x8 ah0 = ldh8(WlA + k0);
    f16x8 ah1 = ldh8(WlA + k0 + 32);
    #pragma unroll
    for (int ss = 0; ss < 4; ++ss) {
      acc[ss] = mm16(ah0, bh[ss][0], acc[ss]);
      acc[ss] = mm16(ah1, bh[ss][1], acc[ss]);
    }
  }

  const int o = o0 + 16 * w + 4 * q;
  f32x4 bv = ld4f(bl + o);
  #pragma unroll
  for (int ss = 0; ss < 4; ++ss) {
    f32x4 v;
    #pragma unroll
    for (int c = 0; c < 4; ++c) v[c] = acc[ss][c] + bv[c];
    *(f32x4*)(out + (size_t)(r0 + 16 * ss + fr) * H_ + o) = v;
  }
}

// ---------------------------------------------------------------------------
extern "C" void kernel_launch(void* const* d_in, const int* in_sizes, int n_in,
                              void* d_out, int out_size, void* d_ws, size_t ws_size,
                              hipStream_t stream) {
  const float* x    = (const float*)d_in[0];
  const int*   mask = (const int*)d_in[1];
  const float* W    = (const float*)d_in[2];
  const float* Wl   = (const float*)d_in[3];
  const float* bl   = (const float*)d_in[4];
  float* out = (float*)d_out;

  const size_t SZ  = (size_t)B_ * NH_ * S_ * P_;      // 4,194,304
  const size_t SZW = (size_t)NH_ * 3 * H_ * P_;       // 3,145,728
  const size_t SZL = (size_t)H_ * H_;                 // 1,048,576
  const size_t SZH = (size_t)B_ * S_ * H_;            // 4,194,304

  char* p = (char*)d_ws;
  f16*   Kh   = (f16*)p;  p += SZ * 2;
  f16*   Qh   = (f16*)p;  p += SZ * 2;
  f16*   VTh  = (f16*)p;  p += SZ * 2;
  f16*   WtH  = (f16*)p;  p += SZW * 2;
  f16*   WlH  = (f16*)p;  p += SZL * 2;
  f16*   hidh = (f16*)p;  p += SZH * 2;
  float* Cbuf = (float*)p; p += (size_t)B_ * NH_ * P_ * 4;
  // total ~42.8 MB

  prep_kernel <<<1792, 256, 0, stream>>>(W, Wl, WtH, WlH);
  qkv_kernel  <<<B_ * NH_ * (S_ / 64), 256, 0, stream>>>(x, WtH, Kh, Qh, VTh);
  hipMemsetAsync(Cbuf, 0, (size_t)B_ * NH_ * P_ * 4, stream);
  stats_kernel<<<B_ * NH_ * (S_ / 128), 256, 0, stream>>>(
      Kh, Qh, VTh, mask, Cbuf);
  av_kernel   <<<B_ * NH_ * (S_ / 64), 256, 0, stream>>>(
      Kh, Qh, VTh, Cbuf, hidh);
  final_kernel<<<(B_ * S_ / 64) * (H_ / 64), 256, 0, stream>>>(
      hidh, WlH, bl, out);
}

// Round 21
// 212.348 us; speedup vs baseline: 1.1187x; 1.0093x over previous
//
#include <hip/hip_runtime.h>

// Problem constants (B,S,H,NH,P) = (2,2048,1024,16,64)
#define B_ 2
#define S_ 2048
#define H_ 1024
#define NH_ 16
#define P_ 64

using f32x4 = __attribute__((ext_vector_type(4))) float;
using i32x4 = __attribute__((ext_vector_type(4))) int;
using f16   = _Float16;
using f16x8 = __attribute__((ext_vector_type(8))) f16;
using f16x4 = __attribute__((ext_vector_type(4))) f16;
using h16x2 = __attribute__((ext_vector_type(2))) __fp16;   // cvt_pkrtz return type

#define QSCALE 0.18033688f   // 0.125 * log2(e): exp(s/8) = exp2(s*QSCALE)

static __device__ __forceinline__ f16x8 ldh8(const f16* p) { return *(const f16x8*)p; }
static __device__ __forceinline__ f32x4 ld4f(const float* p) { return *(const f32x4*)p; }

static __device__ __forceinline__ f32x4 mm16(f16x8 a, f16x8 b, f32x4 c) {
  return __builtin_amdgcn_mfma_f32_16x16x32_f16(a, b, c, 0, 0, 0);
}

// ---------------------------------------------------------------------------
// Prep (merged): blocks [0,768): transpose W -> Wt fp16 [NH][3][P][H];
// blocks [768,1792): convert Wl -> fp16.
// ---------------------------------------------------------------------------
__global__ __launch_bounds__(256) void prep_kernel(
    const float* __restrict__ W, const float* __restrict__ Wl,
    f16* __restrict__ WtH, f16* __restrict__ WlH)
{
  __shared__ float T[64 * 65];
  const int tid = threadIdx.x;
  if (blockIdx.x < 768) {
    const int nt = blockIdx.x >> 4;
    const int h0 = (blockIdx.x & 15) * 64;
    const float* src = W + (size_t)nt * H_ * P_ + (size_t)h0 * P_;
    #pragma unroll
    for (int r = 0; r < 4; ++r) {
      int idx = tid + r * 256;
      int h = idx >> 4, p4 = (idx & 15) << 2;
      f32x4 v = ld4f(src + (size_t)h * P_ + p4);
      #pragma unroll
      for (int i = 0; i < 4; ++i) T[(p4 + i) * 65 + h] = v[i];
    }
    __syncthreads();
    f16* dh = WtH + (size_t)nt * P_ * H_;
    #pragma unroll
    for (int r = 0; r < 4; ++r) {
      int idx = tid + r * 256;
      int p = idx >> 4, h4 = (idx & 15) << 2;
      f16x4 hv;
      #pragma unroll
      for (int i = 0; i < 4; ++i) hv[i] = (f16)T[p * 65 + h4 + i];
      *(f16x4*)(dh + (size_t)p * H_ + h0 + h4) = hv;
    }
  } else {
    int idx = (blockIdx.x - 768) * 256 + tid;
    f32x4 v = ((const f32x4*)Wl)[idx];
    f16x4 h;
    #pragma unroll
    for (int i = 0; i < 4; ++i) h[i] = (f16)v[i];
    ((f16x4*)WlH)[idx] = h;
  }
}

// ---------------------------------------------------------------------------
// Kernel 1: QKV via single fp16 MFMA. x tile (64s x 64k) staged fp16 in LDS,
// double-buffered, chunk-XOR swizzled. Q pre-scaled by 0.125*log2e.
// XCD-swizzled grid: blocks sharing bn land on one XCD (Wt L2 locality).
// ---------------------------------------------------------------------------
__global__ __launch_bounds__(256) void qkv_kernel(
    const float* __restrict__ x, const f16* __restrict__ WtH,
    f16* __restrict__ Kh, f16* __restrict__ Qh, f16* __restrict__ VTh)
{
  __shared__ f16 xls[2][64 * 64];

  const int g = blockIdx.x;
  const int xcd = g & 7, slot = g >> 3;          // 128 slots per XCD
  const int bn = xcd * 4 + (slot >> 5);          // 4 bns per XCD
  const int st = slot & 31;
  const int n = bn & 15;
  const int b = bn >> 4;
  const int s0 = st * 64;
  const int tid = threadIdx.x;
  const int w = tid >> 6, lane = tid & 63, q = lane >> 4, fr = lane & 15;

  const int srow = tid >> 2, scc = tid & 3;
  const float* xsrc = x + ((size_t)b * S_ + s0 + srow) * H_ + 16 * scc;
  const int c0 = ((2 * scc) ^ (srow & 7)) * 8;
  const int c1 = ((2 * scc + 1) ^ (srow & 7)) * 8;

  auto stage = [&](int k0, int bs) {
    f32x4 v0 = ld4f(xsrc + k0),     v1 = ld4f(xsrc + k0 + 4);
    f32x4 v2 = ld4f(xsrc + k0 + 8), v3 = ld4f(xsrc + k0 + 12);
    f16x8 a, b2;
    #pragma unroll
    for (int e = 0; e < 4; ++e) {
      a[e] = (f16)v0[e];  a[e + 4] = (f16)v1[e];
      b2[e] = (f16)v2[e]; b2[e + 4] = (f16)v3[e];
    }
    *(f16x8*)&xls[bs][srow * 64 + c0] = a;
    *(f16x8*)&xls[bs][srow * 64 + c1] = b2;
  };

  const f16* WtK = WtH + ((size_t)(n * 3 + 0) * P_ + 16 * w + fr) * H_ + 8 * q;
  const f16* WtV = WtH + ((size_t)(n * 3 + 1) * P_ + 16 * w + fr) * H_ + 8 * q;
  const f16* WtQ = WtH + ((size_t)(n * 3 + 2) * P_ + 16 * w + fr) * H_ + 8 * q;

  f32x4 accK[4] = {}, accQ[4] = {}, accV[4] = {};

  stage(0, 0);
  for (int step = 0; step < 16; ++step) {
    __syncthreads();
    if (step < 15) stage((step + 1) * 64, (step + 1) & 1);
    const int bs = step & 1;
    const int k0 = step * 64;

    f16x8 xf[4][2];
    #pragma unroll
    for (int ss = 0; ss < 4; ++ss) {
      int row = 16 * ss + fr;
      #pragma unroll
      for (int ks = 0; ks < 2; ++ks) {
        int ch = ((q + 4 * ks) ^ (row & 7)) * 8;
        xf[ss][ks] = *(const f16x8*)&xls[bs][row * 64 + ch];
      }
    }
    f16x8 wk0 = ldh8(WtK + k0), wk1 = ldh8(WtK + k0 + 32);
    f16x8 wq0 = ldh8(WtQ + k0), wq1 = ldh8(WtQ + k0 + 32);
    f16x8 wv0 = ldh8(WtV + k0), wv1 = ldh8(WtV + k0 + 32);
    #pragma unroll
    for (int ss = 0; ss < 4; ++ss) {
      accK[ss] = mm16(wk0, xf[ss][0], accK[ss]);
      accK[ss] = mm16(wk1, xf[ss][1], accK[ss]);
      accQ[ss] = mm16(wq0, xf[ss][0], accQ[ss]);
      accQ[ss] = mm16(wq1, xf[ss][1], accQ[ss]);
      accV[ss] = mm16(xf[ss][0], wv0, accV[ss]);
      accV[ss] = mm16(xf[ss][1], wv1, accV[ss]);
    }
  }

  #pragma unroll
  for (int ss = 0; ss < 4; ++ss) {
    f16x4 hK, hQ;
    #pragma unroll
    for (int c = 0; c < 4; ++c) {
      hK[c] = (f16)accK[ss][c];
      hQ[c] = (f16)(accQ[ss][c] * QSCALE);
    }
    size_t off = ((size_t)bn * S_ + (s0 + 16 * ss + fr)) * P_ + 16 * w + 4 * q;
    *(f16x4*)(Kh + off) = hK;
    *(f16x4*)(Qh + off) = hQ;
  }
  #pragma unroll
  for (int ss = 0; ss < 4; ++ss) {
    f16x4 hV;
    #pragma unroll
    for (int c = 0; c < 4; ++c) hV[c] = (f16)accV[ss][c];
    size_t off = ((size_t)bn * P_ + (16 * w + fr)) * S_ + s0 + 16 * ss + 4 * q;
    *(f16x4*)(VTh + off) = hV;
  }
}

// ---------------------------------------------------------------------------
// Kernel 2: column sum-exp2, j-tile 128 (grid 512), barrier-free main loop.
// XCD-swizzled grid (4 bns per XCD). FUSED epilogue: V' = mask ? zinv*V : 0
// written back PERMUTED within each 32-col chunk (matches av's register-
// resident E mapping). Atomic C partial.
// ---------------------------------------------------------------------------
__global__ __launch_bounds__(256) void stats_kernel(
    const f16* __restrict__ Kh, const f16* __restrict__ Qh,
    f16* __restrict__ VT, const int* __restrict__ mask,
    float* __restrict__ Cbuf)
{
  __shared__ float zbuf[2 * 128];
  const int tid = threadIdx.x;
  const int g = blockIdx.x;
  const int xcd = g & 7, slot = g >> 3;          // 64 slots per XCD
  const int bn = xcd * 4 + (slot >> 4);          // 4 bns per XCD
  const int j0 = (slot & 15) * 128;
  const int w = tid >> 6, lane = tid & 63, q = lane >> 4, fr = lane & 15;
  const int jb = 64 * (w & 1), ih = w >> 1, ib0 = 32 * ih;

  f16x8 qf[4][2];
  #pragma unroll
  for (int jt = 0; jt < 4; ++jt)
    #pragma unroll
    for (int ks = 0; ks < 2; ++ks)
      qf[jt][ks] = ldh8(Qh + ((size_t)bn * S_ + (j0 + jb + 16 * jt + fr)) * P_ + 8 * q + 32 * ks);

  f32x4 z[4] = {};
  f16x8 kA[2][2], kB[2][2];

  auto loadK = [&](f16x8 (&kf)[2][2], int i0) {
    #pragma unroll
    for (int it = 0; it < 2; ++it)
      #pragma unroll
      for (int ks = 0; ks < 2; ++ks)
        kf[it][ks] = ldh8(Kh + ((size_t)bn * S_ + (i0 + ib0 + 16 * it + fr)) * P_ + 8 * q + 32 * ks);
  };
  auto step = [&](f16x8 (&kf)[2][2]) {
    f32x4 sc[4][2] = {};
    __builtin_amdgcn_s_setprio(1);
    #pragma unroll
    for (int ks = 0; ks < 2; ++ks)
      #pragma unroll
      for (int jt = 0; jt < 4; ++jt)
        #pragma unroll
        for (int it = 0; it < 2; ++it)
          sc[jt][it] = mm16(qf[jt][ks], kf[it][ks], sc[jt][it]);
    __builtin_amdgcn_s_setprio(0);
    #pragma unroll
    for (int jt = 0; jt < 4; ++jt)
      #pragma unroll
      for (int c = 0; c < 4; ++c)
        z[jt][c] += exp2f(sc[jt][0][c]) + exp2f(sc[jt][1][c]);
  };

  loadK(kA, 0);
  for (int i0 = 0; i0 < S_; i0 += 128) {
    loadK(kB, i0 + 64);
    step(kA);
    loadK(kA, (i0 + 128) & (S_ - 1));
    step(kB);
  }

  #pragma unroll
  for (int msk = 1; msk <= 8; msk <<= 1)
    #pragma unroll
    for (int jt = 0; jt < 4; ++jt)
      #pragma unroll
      for (int c = 0; c < 4; ++c)
        z[jt][c] += __shfl_xor(z[jt][c], msk, 64);

  if (fr == 0) {
    #pragma unroll
    for (int jt = 0; jt < 4; ++jt)
      *(f32x4*)&zbuf[ih * 128 + jb + 16 * jt + 4 * q] = z[jt];
  }
  __syncthreads();
  if (tid < 128)
    zbuf[tid] = 1.0f / (zbuf[tid] + zbuf[128 + tid]);   // zinv for local j
  __syncthreads();

  // ---- fused V-scale + permuted write + C partial over this j-tile ----
  const int sp = tid >> 2;             // p row 0..63
  const int jc = (tid & 3) * 32;       // 32-col chunk within tile
  f16* vrow = VT + ((size_t)bn * P_ + sp) * S_ + j0 + jc;
  const int* mr = mask + (size_t)(bn >> 4) * S_ + j0 + jc;
  float acc = 0.0f;
  f16 lo[32];                          // logical-indexed scaled values
  #pragma unroll
  for (int k = 0; k < 4; ++k) {
    f16x8 v = *(const f16x8*)(vrow + 8 * k);
    i32x4 m0 = *(const i32x4*)(mr + 8 * k);
    i32x4 m1 = *(const i32x4*)(mr + 8 * k + 4);
    #pragma unroll
    for (int e = 0; e < 4; ++e) {
      float fv = (float)v[e];
      if (m0[e] != 0) lo[8 * k + e] = (f16)(fv * zbuf[jc + 8 * k + e]);
      else { lo[8 * k + e] = (f16)0.0f; acc += fv; }
      float fv2 = (float)v[e + 4];
      if (m1[e] != 0) lo[8 * k + e + 4] = (f16)(fv2 * zbuf[jc + 8 * k + e + 4]);
      else { lo[8 * k + e + 4] = (f16)0.0f; acc += fv2; }
    }
  }
  // permuted write: physical p holds logical l(p) = 4*(p>>3)+(p&3)+((p&4)?16:0)
  #pragma unroll
  for (int k2 = 0; k2 < 4; ++k2) {
    f16x8 o;
    #pragma unroll
    for (int e = 0; e < 8; ++e) {
      const int l = 4 * k2 + (e & 3) + ((e & 4) ? 16 : 0);
      o[e] = lo[l];
    }
    *(f16x8*)(vrow + 8 * k2) = o;
  }
  acc += __shfl_xor(acc, 1, 64);
  acc += __shfl_xor(acc, 2, 64);
  if ((tid & 3) == 0) atomicAdd(&Cbuf[bn * P_ + sp], acc * (1.0f / S_));
}

// ---------------------------------------------------------------------------
// Kernel 3: AV pass, fully register-resident hot loop. i-tile 64, grid 1024,
// 4 waves; XCD-swizzled (4 bns per XCD -> K/Q/V L2-resident per XCD).
// Wave w owns j {T*128+w*32}. 16 QK + 16 PV mfma + 32 exp2 per step.
// ---------------------------------------------------------------------------
__global__ __launch_bounds__(256) void av_kernel(
    const f16* __restrict__ Kh, const f16* __restrict__ Qh,
    const f16* __restrict__ VT, const float* __restrict__ Cbuf,
    f16* __restrict__ hidh)
{
  __shared__ __align__(16) float accl[64 * 68];
  const int tid = threadIdx.x;
  const int g = blockIdx.x;
  const int xcd = g & 7, slot = g >> 3;          // 128 slots per XCD
  const int bn = xcd * 4 + (slot >> 5);          // 4 bns per XCD
  const int i0 = (slot & 31) * 64;
  const int b = bn >> 4, n = bn & 15;
  const int w = tid >> 6, lane = tid & 63, q = lane >> 4, fr = lane & 15;

  f16x8 kf[4][2];
  #pragma unroll
  for (int it = 0; it < 4; ++it)
    #pragma unroll
    for (int ks = 0; ks < 2; ++ks)
      kf[it][ks] = ldh8(Kh + ((size_t)bn * S_ + (i0 + 16 * it + fr)) * P_ + 8 * q + 32 * ks);

  const f16* qp  = Qh + ((size_t)bn * S_ + (w * 32 + fr)) * P_ + 8 * q;
  const f16* vp0 = VT + ((size_t)bn * P_ + fr) * S_ + w * 32 + 8 * q;
  const f16* vp1 = vp0 + (size_t)16 * S_;
  const f16* vp2 = vp0 + (size_t)32 * S_;
  const f16* vp3 = vp0 + (size_t)48 * S_;

  f32x4 opv[4][4] = {};   // [pt][it]: p = 16pt+4q+c, i = 16it+fr

  for (int T = 0; T < 16; ++T) {
    f16x8 aq00 = ldh8(qp);           // jt=0 ks=0
    f16x8 aq01 = ldh8(qp + 32);      // jt=0 ks=1
    f16x8 aq10 = ldh8(qp + 1024);    // jt=1 ks=0
    f16x8 aq11 = ldh8(qp + 1056);    // jt=1 ks=1
    f16x8 va0 = ldh8(vp0), va1 = ldh8(vp1), va2 = ldh8(vp2), va3 = ldh8(vp3);
    qp += 128 * 64;
    vp0 += 128; vp1 += 128; vp2 += 128; vp3 += 128;

    #pragma unroll
    for (int it = 0; it < 4; ++it) {
      f32x4 s0 = {}, s1 = {};
      s0 = mm16(aq00, kf[it][0], s0);
      s0 = mm16(aq01, kf[it][1], s0);
      s1 = mm16(aq10, kf[it][0], s1);
      s1 = mm16(aq11, kf[it][1], s1);
      // register-resident E: physical k=8q+e holds logical j
      // {4q+c (e<4), 16+4q+c (e>=4)} — matches VT's permutation.
      union { f16x8 v8; h16x2 h[4]; } ef;
      ef.h[0] = __builtin_amdgcn_cvt_pkrtz(exp2f(s0[0]), exp2f(s0[1]));
      ef.h[1] = __builtin_amdgcn_cvt_pkrtz(exp2f(s0[2]), exp2f(s0[3]));
      ef.h[2] = __builtin_amdgcn_cvt_pkrtz(exp2f(s1[0]), exp2f(s1[1]));
      ef.h[3] = __builtin_amdgcn_cvt_pkrtz(exp2f(s1[2]), exp2f(s1[3]));
      opv[0][it] = mm16(va0, ef.v8, opv[0][it]);
      opv[1][it] = mm16(va1, ef.v8, opv[1][it]);
      opv[2][it] = mm16(va2, ef.v8, opv[2][it]);
      opv[3][it] = mm16(va3, ef.v8, opv[3][it]);
    }
  }

  // ---- epilogue: reduce 4 wave-partials via LDS ----
  #pragma unroll
  for (int r = 0; r < 4; ++r) {
    __syncthreads();
    if (w == r) {
      #pragma unroll
      for (int it = 0; it < 4; ++it)
        #pragma unroll
        for (int pt = 0; pt < 4; ++pt) {
          float* a = &accl[(16 * it + fr) * 68 + 16 * pt + 4 * q];
          if (r == 0) *(f32x4*)a = opv[pt][it];
          else {
            f32x4 old = *(const f32x4*)a;
            #pragma unroll
            for (int c = 0; c < 4; ++c) old[c] += opv[pt][it][c];
            *(f32x4*)a = old;
          }
        }
    }
  }
  __syncthreads();

  const int ti = tid >> 2;
  const int tp = (tid & 3) << 4;
  const float* cb = Cbuf + bn * P_ + tp;
  f16* dst = hidh + ((size_t)b * S_ + (i0 + ti)) * H_ + n * P_ + tp;
  #pragma unroll
  for (int h = 0; h < 2; ++h) {
    f32x4 a0 = *(const f32x4*)&accl[ti * 68 + tp + 8 * h];
    f32x4 a1 = *(const f32x4*)&accl[ti * 68 + tp + 8 * h + 4];
    f32x4 c0 = ld4f(cb + 8 * h);
    f32x4 c1 = ld4f(cb + 8 * h + 4);
    f16x8 o;
    #pragma unroll
    for (int e = 0; e < 4; ++e) {
      o[e]     = (f16)(a0[e] + c0[e]);
      o[e + 4] = (f16)(a1[e] + c1[e]);
    }
    *(f16x8*)(dst + 8 * h) = o;
  }
}

// ---------------------------------------------------------------------------
// Kernel 4: out = hid @ Wl.T + bl via fp16 MFMA. BK=64, hid tile staged in
// LDS, double-buffered, chunk-XOR swizzled. XCD-swizzled by rt-group.
// ---------------------------------------------------------------------------
__global__ __launch_bounds__(256) void final_kernel(
    const f16* __restrict__ hidh, const f16* __restrict__ WlH,
    const float* __restrict__ bl, float* __restrict__ out)
{
  __shared__ f16 hl[2][64 * 64];
  const int tid = threadIdx.x;
  const int g = blockIdx.x;
  const int xcd = g & 7, slot = g >> 3;          // 128 slots per XCD
  const int rt = xcd * 8 + (slot >> 4);          // 8 rts per XCD
  const int ot = slot & 15;
  const int r0 = rt * 64, o0 = ot * 64;
  const int w = tid >> 6, lane = tid & 63, q = lane >> 4, fr = lane & 15;

  const int srow = tid >> 2, scc = tid & 3;
  const f16* hsrc = hidh + (size_t)(r0 + srow) * H_ + 16 * scc;
  const int c0 = ((2 * scc) ^ (srow & 7)) * 8;
  const int c1 = ((2 * scc + 1) ^ (srow & 7)) * 8;

  auto stage = [&](int k0, int bs) {
    f16x8 a = ldh8(hsrc + k0);
    f16x8 b2 = ldh8(hsrc + k0 + 8);
    *(f16x8*)&hl[bs][srow * 64 + c0] = a;
    *(f16x8*)&hl[bs][srow * 64 + c1] = b2;
  };

  const f16* WlA = WlH + ((size_t)(o0 + 16 * w + fr)) * H_ + 8 * q;

  f32x4 acc[4] = {};

  stage(0, 0);
  for (int step = 0; step < 16; ++step) {
    __syncthreads();
    if (step < 15) stage((step + 1) * 64, (step + 1) & 1);
    const int bs = step & 1;
    const int k0 = step * 64;

    f16x8 bh[4][2];
    #pragma unroll
    for (int ss = 0; ss < 4; ++ss) {
      int row = 16 * ss + fr;
      #pragma unroll
      for (int ks = 0; ks < 2; ++ks) {
        int ch = ((q + 4 * ks) ^ (row & 7)) * 8;
        bh[ss][ks] = *(const f16x8*)&hl[bs][row * 64 + ch];
      }
    }
    f16x8 ah0 = ldh8(WlA + k0);
    f16x8 ah1 = ldh8(WlA + k0 + 32);
    #pragma unroll
    for (int ss = 0; ss < 4; ++ss) {
      acc[ss] = mm16(ah0, bh[ss][0], acc[ss]);
      acc[ss] = mm16(ah1, bh[ss][1], acc[ss]);
    }
  }

  const int o = o0 + 16 * w + 4 * q;
  f32x4 bv = ld4f(bl + o);
  #pragma unroll
  for (int ss = 0; ss < 4; ++ss) {
    f32x4 v;
    #pragma unroll
    for (int c = 0; c < 4; ++c) v[c] = acc[ss][c] + bv[c];
    *(f32x4*)(out + (size_t)(r0 + 16 * ss + fr) * H_ + o) = v;
  }
}

// ---------------------------------------------------------------------------
extern "C" void kernel_launch(void* const* d_in, const int* in_sizes, int n_in,
                              void* d_out, int out_size, void* d_ws, size_t ws_size,
                              hipStream_t stream) {
  const float* x    = (const float*)d_in[0];
  const int*   mask = (const int*)d_in[1];
  const float* W    = (const float*)d_in[2];
  const float* Wl   = (const float*)d_in[3];
  const float* bl   = (const float*)d_in[4];
  float* out = (float*)d_out;

  const size_t SZ  = (size_t)B_ * NH_ * S_ * P_;      // 4,194,304
  const size_t SZW = (size_t)NH_ * 3 * H_ * P_;       // 3,145,728
  const size_t SZL = (size_t)H_ * H_;                 // 1,048,576
  const size_t SZH = (size_t)B_ * S_ * H_;            // 4,194,304

  char* p = (char*)d_ws;
  f16*   Kh   = (f16*)p;  p += SZ * 2;
  f16*   Qh   = (f16*)p;  p += SZ * 2;
  f16*   VTh  = (f16*)p;  p += SZ * 2;
  f16*   WtH  = (f16*)p;  p += SZW * 2;
  f16*   WlH  = (f16*)p;  p += SZL * 2;
  f16*   hidh = (f16*)p;  p += SZH * 2;
  float* Cbuf = (float*)p; p += (size_t)B_ * NH_ * P_ * 4;
  // total ~42.8 MB

  prep_kernel <<<1792, 256, 0, stream>>>(W, Wl, WtH, WlH);
  qkv_kernel  <<<B_ * NH_ * (S_ / 64), 256, 0, stream>>>(x, WtH, Kh, Qh, VTh);
  hipMemsetAsync(Cbuf, 0, (size_t)B_ * NH_ * P_ * 4, stream);
  stats_kernel<<<B_ * NH_ * (S_ / 128), 256, 0, stream>>>(
      Kh, Qh, VTh, mask, Cbuf);
  av_kernel   <<<B_ * NH_ * (S_ / 64), 256, 0, stream>>>(
      Kh, Qh, VTh, Cbuf, hidh);
  final_kernel<<<(B_ * S_ / 64) * (H_ / 64), 256, 0, stream>>>(
      hidh, WlH, bl, out);
}